// Round 4
// baseline (311.053 us; speedup 1.0000x reference)
//
#include <hip/hip_runtime.h>
#include <math.h>

typedef __bf16 bf16_t;
typedef __bf16 bfrag8 __attribute__((ext_vector_type(8)));
typedef float  facc4  __attribute__((ext_vector_type(4)));

__device__ inline unsigned short f2b(float x) {          // RNE float->bf16 bits
    unsigned int u = __float_as_uint(x);
    unsigned int r = (u + 0x7fffu + ((u >> 16) & 1u)) >> 16;
    return (unsigned short)r;
}
__device__ inline unsigned int pack2(float lo, float hi) {
    return (unsigned int)f2b(lo) | ((unsigned int)f2b(hi) << 16);
}
__device__ inline float blo(unsigned int q) { return __uint_as_float(q << 16); }
__device__ inline float bhi(unsigned int q) { return __uint_as_float(q & 0xffff0000u); }

// ---------------- CSR build ----------------

__global__ void k_count(const int* __restrict__ dst, int* __restrict__ cnt, int E) {
    int e = blockIdx.x * 256 + threadIdx.x;
    if (e < E) atomicAdd(&cnt[dst[e]], 1);
}

__global__ void k_dinv(const int* __restrict__ cnt, float* __restrict__ dinv, int N) {
    int i = blockIdx.x * 256 + threadIdx.x;
    if (i < N) dinv[i] = rsqrtf((float)(cnt[i] + 1));   // +1 = self loop
}

__global__ void k_scan1(const int* __restrict__ cnt, int* __restrict__ offs,
                        int* __restrict__ bsum, int N) {
    __shared__ int sm[256];
    int t = threadIdx.x, i = blockIdx.x * 256 + t;
    int v = (i < N) ? cnt[i] : 0;
    sm[t] = v;
    __syncthreads();
    for (int off = 1; off < 256; off <<= 1) {
        int x = (t >= off) ? sm[t - off] : 0;
        __syncthreads();
        sm[t] += x;
        __syncthreads();
    }
    if (i < N) offs[i] = sm[t] - v;
    if (t == 255) bsum[blockIdx.x] = sm[255];
}

__global__ void k_scan2(const int* __restrict__ bsum, int* __restrict__ boff, int nb) {
    __shared__ int sm[256];
    int t = threadIdx.x;
    int v = (t < nb) ? bsum[t] : 0;
    sm[t] = v;
    __syncthreads();
    for (int off = 1; off < 256; off <<= 1) {
        int x = (t >= off) ? sm[t - off] : 0;
        __syncthreads();
        sm[t] += x;
        __syncthreads();
    }
    if (t < nb) boff[t] = sm[t] - v;
}

__global__ void k_scan3(int* __restrict__ offs, const int* __restrict__ boff, int N, int E) {
    int t = threadIdx.x, i = blockIdx.x * 256 + t;
    if (i < N) offs[i] += boff[blockIdx.x];
    if (blockIdx.x == 0 && t == 0) offs[N] = E;
}

// XCD-partitioned fill: group g (= bid&7, round-robins onto XCDs) scatters only
// edges whose dst is in node-range g. Each CSR bucket line is then written by one
// XCD's L2 only -> full-line writebacks (fixes 8x partial-line WRITE inflation).
// Correctness does NOT depend on the block->XCD mapping (atomic slots).
__global__ __launch_bounds__(256) void k_fill_x(const int* __restrict__ src,
                                                const int* __restrict__ dst,
                                                const int* __restrict__ offs,
                                                int* __restrict__ cur,
                                                const float* __restrict__ dinv,
                                                int2* __restrict__ csr, int E, int N) {
    int g  = blockIdx.x & 7;
    int bb = blockIdx.x >> 3;
    int nb = gridDim.x >> 3;
    int lo = (int)((long long)N * g >> 3);
    int hi = (int)((long long)N * (g + 1) >> 3);
    for (int e = bb * 256 + threadIdx.x; e < E; e += nb * 256) {
        int d = dst[e];
        if (d >= lo && d < hi) {
            int s = src[e];
            int p = offs[d] + atomicAdd(&cur[d], 1);
            csr[p] = make_int2(s, __float_as_int(dinv[s]));
        }
    }
}

// ---------------- fp32 -> bf16 conversion (8 elems/thread) ----------------
__global__ void k_cvt(const float* __restrict__ in, unsigned int* __restrict__ outb, int n8) {
    int i = blockIdx.x * 256 + threadIdx.x;
    if (i >= n8) return;
    const float4* p = (const float4*)in + (size_t)i * 2;
    float4 a = p[0], b = p[1];
    uint4 o;
    o.x = pack2(a.x, a.y);
    o.y = pack2(a.z, a.w);
    o.z = pack2(b.x, b.y);
    o.w = pack2(b.z, b.w);
    ((uint4*)outb)[i] = o;
}

// ---------------- weight transpose + cvt: Wt[n][k] = (bf16)W[k][n] ----------------
__global__ void k_prep_wt(const float* __restrict__ W, unsigned short* __restrict__ Wt,
                          int K, int N) {
    int idx = blockIdx.x * 256 + threadIdx.x;
    if (idx >= K * N) return;
    int n = idx / K, k = idx - n * K;
    Wt[idx] = f2b(W[(size_t)k * N + n]);
}

// ---------------- MFMA GEMM: [M x 128](bf16) @ Bt[128][128](bf16) -> [M x 128](bf16)
__global__ __launch_bounds__(256) void k_gemm_nn128(const bf16_t* __restrict__ A,
                                                    const bf16_t* __restrict__ Bt,
                                                    bf16_t* __restrict__ out, int M) {
    __shared__ bf16_t As[64 * 136];
    __shared__ bf16_t Bs[128 * 136];
    int t = threadIdx.x;
    int wave = t >> 6, lane = t & 63, quad = lane >> 4, l16 = lane & 15;
    int r0 = blockIdx.x * 64;
#pragma unroll
    for (int i = 0; i < 4; ++i) {
        int chunk = t + i * 256;
        int row = chunk >> 4, c8 = (chunk & 15) << 3;
        int gr = r0 + row;
        uint4 v = make_uint4(0u, 0u, 0u, 0u);
        if (gr < M) v = *(const uint4*)&A[(size_t)gr * 128 + c8];
        *(uint4*)&As[row * 136 + c8] = v;
    }
#pragma unroll
    for (int i = 0; i < 8; ++i) {
        int chunk = t + i * 256;
        int row = chunk >> 4, c8 = (chunk & 15) << 3;
        *(uint4*)&Bs[row * 136 + c8] = *(const uint4*)&Bt[row * 128 + c8];
    }
    __syncthreads();

    facc4 acc[8];
#pragma unroll
    for (int nt = 0; nt < 8; ++nt) acc[nt] = (facc4){0.f, 0.f, 0.f, 0.f};
    int arow = (wave << 4) + l16;
#pragma unroll
    for (int ks = 0; ks < 4; ++ks) {
        int kk = ks * 32 + quad * 8;
        bfrag8 af = *(const bfrag8*)&As[arow * 136 + kk];
#pragma unroll
        for (int nt = 0; nt < 8; ++nt) {
            bfrag8 bf = *(const bfrag8*)&Bs[(nt * 16 + l16) * 136 + kk];
            acc[nt] = __builtin_amdgcn_mfma_f32_16x16x32_bf16(af, bf, acc[nt], 0, 0, 0);
        }
    }
    int rbase = r0 + (wave << 4) + quad * 4;
#pragma unroll
    for (int nt = 0; nt < 8; ++nt) {
        int col = nt * 16 + l16;
#pragma unroll
        for (int r = 0; r < 4; ++r) {
            int row = rbase + r;
            if (row < M) {
                unsigned short b = f2b(acc[nt][r]);
                ((unsigned short*)out)[(size_t)row * 128 + col] = b;
            }
        }
    }
}

// ---------------- aggregation (bf16 h): wave per node, 8-way MLP unroll ----------------
__global__ __launch_bounds__(256) void k_agg_b(const unsigned int* __restrict__ hx,  // [N][64]
                                               const int2* __restrict__ csr,
                                               const int* __restrict__ offs,
                                               const float* __restrict__ dinv,
                                               const float* __restrict__ bias,
                                               unsigned int* __restrict__ out, int N) {
    int node = blockIdx.x * 4 + (threadIdx.x >> 6);
    int lane = threadIdx.x & 63;
    if (node >= N) return;
    float di = dinv[node];
    unsigned int q = hx[(size_t)node * 64 + lane];
    float acc0 = blo(q) * di, acc1 = bhi(q) * di;     // self-loop (x di again at end)
    int s0 = offs[node], s1 = offs[node + 1];
    for (int base = s0; base < s1; base += 64) {
        int nloc = min(64, s1 - base);
        int2 en = make_int2(0, 0);
        if (lane < nloc) en = csr[base + lane];
        int j = 0;
        for (; j + 8 <= nloc; j += 8) {
            int sid[8]; float w[8]; unsigned int g[8];
#pragma unroll
            for (int u = 0; u < 8; ++u) {
                sid[u] = __shfl(en.x, j + u, 64);
                w[u]   = __int_as_float(__shfl(en.y, j + u, 64));
            }
#pragma unroll
            for (int u = 0; u < 8; ++u) g[u] = hx[(size_t)sid[u] * 64 + lane];  // 8 in flight
#pragma unroll
            for (int u = 0; u < 8; ++u) { acc0 += blo(g[u]) * w[u]; acc1 += bhi(g[u]) * w[u]; }
        }
        for (; j + 4 <= nloc; j += 4) {
            int sid[4]; float w[4]; unsigned int g[4];
#pragma unroll
            for (int u = 0; u < 4; ++u) {
                sid[u] = __shfl(en.x, j + u, 64);
                w[u]   = __int_as_float(__shfl(en.y, j + u, 64));
            }
#pragma unroll
            for (int u = 0; u < 4; ++u) g[u] = hx[(size_t)sid[u] * 64 + lane];
#pragma unroll
            for (int u = 0; u < 4; ++u) { acc0 += blo(g[u]) * w[u]; acc1 += bhi(g[u]) * w[u]; }
        }
        for (; j < nloc; ++j) {
            int srcn = __shfl(en.x, j, 64);
            float w  = __int_as_float(__shfl(en.y, j, 64));
            unsigned int g = hx[(size_t)srcn * 64 + lane];
            acc0 += blo(g) * w;
            acc1 += bhi(g) * w;
        }
    }
    float2 bb = *(const float2*)&bias[lane * 2];
    float v0 = fmaxf(acc0 * di + bb.x, 0.f);
    float v1 = fmaxf(acc1 * di + bb.y, 0.f);
    out[(size_t)node * 64 + lane] = pack2(v0, v1);
}

// ---------------- entity mean pool (bf16 in/out): wave per row ----------------
__global__ __launch_bounds__(256) void k_pool_b(const unsigned int* __restrict__ h,
                                                const int* __restrict__ ent,
                                                unsigned int* __restrict__ out) {
    int r = blockIdx.x * 4 + (threadIdx.x >> 6);
    int lane = threadIdx.x & 63;
    float a0 = 0.f, a1 = 0.f;
    int cnt = 0;
#pragma unroll
    for (int m = 0; m < 20; ++m) {
        int id = ent[r * 20 + m];
        if (id >= 0) {
            unsigned int q = h[(size_t)id * 64 + lane];
            a0 += blo(q); a1 += bhi(q); cnt++;
        }
    }
    float inv = 1.f / (float)max(cnt, 1);
    out[(size_t)r * 64 + lane] = pack2(a0 * inv, a1 * inv);
}

// ---------------- MLP fc1 (MFMA): z = relu([bertb|gnnb] @ fc1wt + fc1_b), z fp32
__global__ __launch_bounds__(256) void k_mlp1_mfma(const bf16_t* __restrict__ bertb,
                                                   const bf16_t* __restrict__ gnnb,
                                                   const bf16_t* __restrict__ fwt,  // [448][896]
                                                   const float* __restrict__ fb,
                                                   float* __restrict__ z) {
    __shared__ bf16_t As[64 * 136];
    __shared__ bf16_t Bs[64 * 136];
    int t = threadIdx.x;
    int wave = t >> 6, lane = t & 63, quad = lane >> 4, l16 = lane & 15;
    int r0 = blockIdx.x * 64, c0 = blockIdx.y * 64;
    facc4 acc[4];
#pragma unroll
    for (int nt = 0; nt < 4; ++nt) acc[nt] = (facc4){0.f, 0.f, 0.f, 0.f};

    for (int ks = 0; ks < 7; ++ks) {
#pragma unroll
        for (int i = 0; i < 4; ++i) {
            int chunk = t + i * 256;
            int row = chunk >> 4, c8 = (chunk & 15) << 3;
            int gr = r0 + row;
            const bf16_t* srcp = (ks < 6) ? &bertb[(size_t)gr * 768 + ks * 128 + c8]
                                          : &gnnb[(size_t)gr * 128 + c8];
            *(uint4*)&As[row * 136 + c8] = *(const uint4*)srcp;
        }
#pragma unroll
        for (int i = 0; i < 4; ++i) {
            int chunk = t + i * 256;
            int row = chunk >> 4, c8 = (chunk & 15) << 3;
            *(uint4*)&Bs[row * 136 + c8] =
                *(const uint4*)&fwt[(size_t)(c0 + row) * 896 + ks * 128 + c8];
        }
        __syncthreads();
        int arow = (wave << 4) + l16;
#pragma unroll
        for (int sub = 0; sub < 4; ++sub) {
            int kk = sub * 32 + quad * 8;
            bfrag8 af = *(const bfrag8*)&As[arow * 136 + kk];
#pragma unroll
            for (int nt = 0; nt < 4; ++nt) {
                bfrag8 bf = *(const bfrag8*)&Bs[(nt * 16 + l16) * 136 + kk];
                acc[nt] = __builtin_amdgcn_mfma_f32_16x16x32_bf16(af, bf, acc[nt], 0, 0, 0);
            }
        }
        __syncthreads();
    }
    int rbase = r0 + (wave << 4) + quad * 4;
#pragma unroll
    for (int nt = 0; nt < 4; ++nt) {
        int col = c0 + nt * 16 + l16;
        float bb = fb[col];
#pragma unroll
        for (int r = 0; r < 4; ++r)
            z[(size_t)(rbase + r) * 448 + col] = fmaxf(acc[nt][r] + bb, 0.f);
    }
}

// ---------------- MLP fc2 + sigmoid: wave per row, 4 rows/block ----------------
__global__ __launch_bounds__(256) void k_mlp2(const float* __restrict__ z,
                                              const float* __restrict__ w,
                                              const float* __restrict__ b,
                                              float* __restrict__ out) {
    int r = blockIdx.x * 4 + (threadIdx.x >> 6);
    int lane = threadIdx.x & 63;
    float acc = 0.f;
#pragma unroll
    for (int i = 0; i < 7; ++i) {
        int c = lane + i * 64;
        acc += z[(size_t)r * 448 + c] * w[c];
    }
#pragma unroll
    for (int off = 32; off > 0; off >>= 1) acc += __shfl_down(acc, off, 64);
    if (lane == 0) {
        float lg = acc + b[0];
        out[r] = 1.f / (1.f + expf(-lg));
    }
}

extern "C" void kernel_launch(void* const* d_in, const int* in_sizes, int n_in,
                              void* d_out, int out_size, void* d_ws, size_t ws_size,
                              hipStream_t stream) {
    const float* bert = (const float*)d_in[0];
    const float* x    = (const float*)d_in[1];
    const int*   ei   = (const int*)d_in[2];
    const int*   ent  = (const int*)d_in[3];
    const float* W1   = (const float*)d_in[4];
    const float* b1   = (const float*)d_in[5];
    const float* W2   = (const float*)d_in[6];
    const float* b2   = (const float*)d_in[7];
    const float* fc1w = (const float*)d_in[8];
    const float* fc1b = (const float*)d_in[9];
    const float* fc2w = (const float*)d_in[10];
    const float* fc2b = (const float*)d_in[11];
    float* out = (float*)d_out;

    const int N = in_sizes[1] / 128;   // 50000
    const int E = in_sizes[2] / 2;     // 800000
    const int B = in_sizes[0] / 768;   // 4096

    const int* srcv = ei;
    const int* dstv = ei + E;

    char* wsp = (char*)d_ws;
    size_t off = 0;
    auto alloc = [&](size_t bytes) -> void* {
        void* p = wsp + off;
        off += (bytes + 255) & ~(size_t)255;
        return p;
    };
    float* dinv   = (float*)alloc((size_t)N * 4);
    int*   incnt  = (int*)alloc((size_t)N * 4);
    int*   cur    = (int*)alloc((size_t)N * 4);
    int*   offs   = (int*)alloc((size_t)(N + 1) * 4);
    int*   bsum   = (int*)alloc(256 * 4);
    int*   boff   = (int*)alloc(256 * 4);
    int2*  csr    = (int2*)alloc((size_t)E * 8);
    bf16_t* xb    = (bf16_t*)alloc((size_t)N * 128 * 2);
    bf16_t* bertb = (bf16_t*)alloc((size_t)B * 768 * 2);
    bf16_t* w1t   = (bf16_t*)alloc(128 * 128 * 2);
    bf16_t* w2t   = (bf16_t*)alloc(128 * 128 * 2);
    bf16_t* fwt   = (bf16_t*)alloc((size_t)896 * 448 * 2);
    bf16_t* gbuf  = (bf16_t*)alloc((size_t)N * 128 * 2);
    bf16_t* hbuf  = (bf16_t*)alloc((size_t)N * 128 * 2);
    bf16_t* gnnb  = (bf16_t*)alloc((size_t)B * 128 * 2);
    float* zbuf   = (float*)alloc((size_t)B * 448 * 4);
    (void)ws_size; (void)n_in; (void)out_size;

    hipMemsetAsync(incnt, 0, (size_t)N * 4, stream);
    hipMemsetAsync(cur, 0, (size_t)N * 4, stream);

    int nb = (N + 255) / 256;
    k_count<<<(E + 255) / 256, 256, 0, stream>>>(dstv, incnt, E);
    k_dinv <<<nb, 256, 0, stream>>>(incnt, dinv, N);
    k_scan1<<<nb, 256, 0, stream>>>(incnt, offs, bsum, N);
    k_scan2<<<1, 256, 0, stream>>>(bsum, boff, nb);
    k_scan3<<<nb, 256, 0, stream>>>(offs, boff, N, E);
    k_fill_x<<<8 * 104, 256, 0, stream>>>(srcv, dstv, offs, cur, dinv, csr, E, N);

    int nx8 = N * 128 / 8, nb8 = B * 768 / 8;
    k_cvt<<<(nx8 + 255) / 256, 256, 0, stream>>>(x, (unsigned int*)xb, nx8);
    k_cvt<<<(nb8 + 255) / 256, 256, 0, stream>>>(bert, (unsigned int*)bertb, nb8);
    k_prep_wt<<<(128 * 128 + 255) / 256, 256, 0, stream>>>(W1, (unsigned short*)w1t, 128, 128);
    k_prep_wt<<<(128 * 128 + 255) / 256, 256, 0, stream>>>(W2, (unsigned short*)w2t, 128, 128);
    k_prep_wt<<<(896 * 448 + 255) / 256, 256, 0, stream>>>(fc1w, (unsigned short*)fwt, 896, 448);

    int gb = (N + 63) / 64;
    k_gemm_nn128<<<gb, 256, 0, stream>>>(xb, w1t, gbuf, N);
    k_agg_b<<<(N + 3) / 4, 256, 0, stream>>>((const unsigned int*)gbuf, csr, offs, dinv, b1,
                                             (unsigned int*)hbuf, N);
    k_gemm_nn128<<<gb, 256, 0, stream>>>(hbuf, w2t, gbuf, N);
    k_agg_b<<<(N + 3) / 4, 256, 0, stream>>>((const unsigned int*)gbuf, csr, offs, dinv, b2,
                                             (unsigned int*)hbuf, N);
    k_pool_b<<<B / 4, 256, 0, stream>>>((const unsigned int*)hbuf, ent, (unsigned int*)gnnb);
    k_mlp1_mfma<<<dim3(B / 64, 7), 256, 0, stream>>>(bertb, gnnb, fwt, fc1b, zbuf);
    k_mlp2<<<B / 4, 256, 0, stream>>>(zbuf, fc2w, fc2b, out);
}

// Round 5
// 290.800 us; speedup vs baseline: 1.0696x; 1.0696x over previous
//
#include <hip/hip_runtime.h>
#include <math.h>

typedef __bf16 bf16_t;
typedef __bf16 bfrag8 __attribute__((ext_vector_type(8)));
typedef float  facc4  __attribute__((ext_vector_type(4)));

#define NBUCK 512   // dst-buckets for CSR multisplit (requires N < 65536 for 16-bit packing)

__device__ inline unsigned short f2b(float x) {          // RNE float->bf16 bits
    unsigned int u = __float_as_uint(x);
    unsigned int r = (u + 0x7fffu + ((u >> 16) & 1u)) >> 16;
    return (unsigned short)r;
}
__device__ inline unsigned int pack2(float lo, float hi) {
    return (unsigned int)f2b(lo) | ((unsigned int)f2b(hi) << 16);
}
__device__ inline float blo(unsigned int q) { return __uint_as_float(q << 16); }
__device__ inline float bhi(unsigned int q) { return __uint_as_float(q & 0xffff0000u); }

__device__ inline int bucket_of(int d, int N) {
    return (int)(((long long)d * NBUCK) / N);
}

// ---------------- degree count / dinv / scan ----------------

__global__ void k_count(const int* __restrict__ dst, int* __restrict__ cnt, int E) {
    int e = blockIdx.x * 256 + threadIdx.x;
    if (e < E) atomicAdd(&cnt[dst[e]], 1);
}

__global__ void k_dinv(const int* __restrict__ cnt, float* __restrict__ dinv, int N) {
    int i = blockIdx.x * 256 + threadIdx.x;
    if (i < N) dinv[i] = rsqrtf((float)(cnt[i] + 1));   // +1 = self loop
}

__global__ void k_scan1(const int* __restrict__ cnt, int* __restrict__ offs,
                        int* __restrict__ bsum, int N) {
    __shared__ int sm[256];
    int t = threadIdx.x, i = blockIdx.x * 256 + t;
    int v = (i < N) ? cnt[i] : 0;
    sm[t] = v;
    __syncthreads();
    for (int off = 1; off < 256; off <<= 1) {
        int x = (t >= off) ? sm[t - off] : 0;
        __syncthreads();
        sm[t] += x;
        __syncthreads();
    }
    if (i < N) offs[i] = sm[t] - v;
    if (t == 255) bsum[blockIdx.x] = sm[255];
}

__global__ void k_scan2(const int* __restrict__ bsum, int* __restrict__ boff, int nb) {
    __shared__ int sm[256];
    int t = threadIdx.x;
    int v = (t < nb) ? bsum[t] : 0;
    sm[t] = v;
    __syncthreads();
    for (int off = 1; off < 256; off <<= 1) {
        int x = (t >= off) ? sm[t - off] : 0;
        __syncthreads();
        sm[t] += x;
        __syncthreads();
    }
    if (t < nb) boff[t] = sm[t] - v;
}

__global__ void k_scan3(int* __restrict__ offs, const int* __restrict__ boff, int N, int E) {
    int t = threadIdx.x, i = blockIdx.x * 256 + t;
    if (i < N) offs[i] += boff[blockIdx.x];
    if (blockIdx.x == 0 && t == 0) offs[N] = E;
}

// ---------------- CSR multisplit ----------------
// btail[b] = offs[lo_b] so the binned edge buffer shares the final CSR layout.
__global__ void k_binit(const int* __restrict__ offs, int* __restrict__ btail, int N) {
    int b = blockIdx.x * 256 + threadIdx.x;
    if (b < NBUCK) btail[b] = offs[(int)(((long long)b * N + NBUCK - 1) / NBUCK)];
}

// Pass 1: LDS multisplit of 4096-edge chunks into NBUCK dst-buckets, then
// wave-coalesced run writes to per-bucket global tails (avoids partial-line
// scatter stores, which HW cannot merge: measured 64B HBM write per 8B store).
__global__ __launch_bounds__(256) void k_bin(const int* __restrict__ src,
                                             const int* __restrict__ dst,
                                             int* __restrict__ btail,
                                             unsigned int* __restrict__ ebuf,
                                             int E, int N) {
    __shared__ unsigned int sorted[4096];
    __shared__ int hist[NBUCK];      // histogram, then scatter cursor
    __shared__ int lstart[NBUCK];
    __shared__ int gbase[NBUCK];
    __shared__ int sm[256];
    int tid = threadIdx.x;
    int base = blockIdx.x * 4096;
    int cnt = min(4096, E - base);
    hist[tid] = 0; hist[tid + 256] = 0;
    __syncthreads();
    unsigned int mye[16]; int myb[16];
#pragma unroll
    for (int i = 0; i < 16; ++i) {
        int idx = i * 256 + tid;
        myb[i] = -1;
        if (idx < cnt) {
            int e = base + idx;
            int s = src[e], d = dst[e];
            mye[i] = ((unsigned int)s << 16) | (unsigned int)d;   // needs s,d < 65536
            int b = bucket_of(d, N);
            myb[i] = b;
            atomicAdd(&hist[b], 1);
        }
    }
    __syncthreads();
    // exclusive scan over NBUCK=512: pairwise + 256-wide Hillis-Steele
    int p0 = hist[2 * tid], p1 = hist[2 * tid + 1];
    sm[tid] = p0 + p1;
    __syncthreads();
    for (int off = 1; off < 256; off <<= 1) {
        int x = (tid >= off) ? sm[tid - off] : 0;
        __syncthreads();
        sm[tid] += x;
        __syncthreads();
    }
    int excl = sm[tid] - (p0 + p1);
    lstart[2 * tid] = excl;
    lstart[2 * tid + 1] = excl + p0;
    __syncthreads();
    hist[tid] = lstart[tid]; hist[tid + 256] = lstart[tid + 256];   // cursors
    __syncthreads();
#pragma unroll
    for (int i = 0; i < 16; ++i) {
        if (myb[i] >= 0) {
            int pos = atomicAdd(&hist[myb[i]], 1);
            sorted[pos] = mye[i];
        }
    }
    __syncthreads();
    for (int b = tid; b < NBUCK; b += 256) {
        int c = hist[b] - lstart[b];
        gbase[b] = (c > 0) ? atomicAdd(&btail[b], c) : 0;
    }
    __syncthreads();
    // coalesced writeout: consecutive idx -> mostly-consecutive dest
    for (int idx = tid; idx < cnt; idx += 256) {
        unsigned int v = sorted[idx];
        int b = bucket_of((int)(v & 0xffffu), N);
        ebuf[gbase[b] + (idx - lstart[b])] = v;
    }
}

// Pass 2: one WG per bucket; per-node scatter inside LDS, then the contiguous
// CSR segment (ushort src ids) streams out coalesced.
#define SEGCAP 16384
__global__ __launch_bounds__(256) void k_build(const unsigned int* __restrict__ ebuf,
                                               const int* __restrict__ offs,
                                               unsigned short* __restrict__ csr,
                                               int N) {
    __shared__ unsigned short seg[SEGCAP];
    __shared__ int curl[256];
    __shared__ int loff[257];
    int b = blockIdx.x, tid = threadIdx.x;
    int lo = (int)(((long long)b * N + NBUCK - 1) / NBUCK);
    int hi = (int)(((long long)(b + 1) * N + NBUCK - 1) / NBUCK);
    int nrange = hi - lo;                       // <= ceil(N/NBUCK) ~ 98
    for (int i = tid; i <= nrange; i += 256) loff[i] = offs[lo + i];
    for (int i = tid; i < nrange; i += 256) curl[i] = 0;
    __syncthreads();
    int segbase = loff[0], segend = loff[nrange];
    int cnt = segend - segbase;
    if (cnt <= SEGCAP) {
        for (int idx = segbase + tid; idx < segend; idx += 256) {
            unsigned int v = ebuf[idx];
            int d = (int)(v & 0xffffu) - lo;
            int local = atomicAdd(&curl[d], 1);
            seg[loff[d] - segbase + local] = (unsigned short)(v >> 16);
        }
        __syncthreads();
        for (int idx = tid; idx < cnt; idx += 256)
            csr[segbase + idx] = seg[idx];
    } else {                                    // statistical never (mean 1562/bucket)
        for (int idx = segbase + tid; idx < segend; idx += 256) {
            unsigned int v = ebuf[idx];
            int d = (int)(v & 0xffffu) - lo;
            int local = atomicAdd(&curl[d], 1);
            csr[loff[d] + local] = (unsigned short)(v >> 16);
        }
    }
}

// ---------------- fp32 -> bf16 conversion (8 elems/thread) ----------------
__global__ void k_cvt(const float* __restrict__ in, unsigned int* __restrict__ outb, int n8) {
    int i = blockIdx.x * 256 + threadIdx.x;
    if (i >= n8) return;
    const float4* p = (const float4*)in + (size_t)i * 2;
    float4 a = p[0], b = p[1];
    uint4 o;
    o.x = pack2(a.x, a.y);
    o.y = pack2(a.z, a.w);
    o.z = pack2(b.x, b.y);
    o.w = pack2(b.z, b.w);
    ((uint4*)outb)[i] = o;
}

// ---------------- weight transpose + cvt: Wt[n][k] = (bf16)W[k][n] ----------------
__global__ void k_prep_wt(const float* __restrict__ W, unsigned short* __restrict__ Wt,
                          int K, int N) {
    int idx = blockIdx.x * 256 + threadIdx.x;
    if (idx >= K * N) return;
    int n = idx / K, k = idx - n * K;
    Wt[idx] = f2b(W[(size_t)k * N + n]);
}

// ---------------- MFMA GEMM: out[m] = (A @ Bt^T)[m] * rs[m]  (bf16 out) --------
// rs = dinv row-scale, folding norm(src) into h so CSR entries need no weight.
__global__ __launch_bounds__(256) void k_gemm_nn128(const bf16_t* __restrict__ A,
                                                    const bf16_t* __restrict__ Bt,
                                                    const float* __restrict__ rs,
                                                    bf16_t* __restrict__ out, int M) {
    __shared__ bf16_t As[64 * 136];
    __shared__ bf16_t Bs[128 * 136];
    int t = threadIdx.x;
    int wave = t >> 6, lane = t & 63, quad = lane >> 4, l16 = lane & 15;
    int r0 = blockIdx.x * 64;
#pragma unroll
    for (int i = 0; i < 4; ++i) {
        int chunk = t + i * 256;
        int row = chunk >> 4, c8 = (chunk & 15) << 3;
        int gr = r0 + row;
        uint4 v = make_uint4(0u, 0u, 0u, 0u);
        if (gr < M) v = *(const uint4*)&A[(size_t)gr * 128 + c8];
        *(uint4*)&As[row * 136 + c8] = v;
    }
#pragma unroll
    for (int i = 0; i < 8; ++i) {
        int chunk = t + i * 256;
        int row = chunk >> 4, c8 = (chunk & 15) << 3;
        *(uint4*)&Bs[row * 136 + c8] = *(const uint4*)&Bt[row * 128 + c8];
    }
    __syncthreads();

    facc4 acc[8];
#pragma unroll
    for (int nt = 0; nt < 8; ++nt) acc[nt] = (facc4){0.f, 0.f, 0.f, 0.f};
    int arow = (wave << 4) + l16;
#pragma unroll
    for (int ks = 0; ks < 4; ++ks) {
        int kk = ks * 32 + quad * 8;
        bfrag8 af = *(const bfrag8*)&As[arow * 136 + kk];
#pragma unroll
        for (int nt = 0; nt < 8; ++nt) {
            bfrag8 bf = *(const bfrag8*)&Bs[(nt * 16 + l16) * 136 + kk];
            acc[nt] = __builtin_amdgcn_mfma_f32_16x16x32_bf16(af, bf, acc[nt], 0, 0, 0);
        }
    }
    int rbase = r0 + (wave << 4) + quad * 4;
#pragma unroll
    for (int r = 0; r < 4; ++r) {
        int row = rbase + r;
        if (row < M) {
            float sc = rs[row];
#pragma unroll
            for (int nt = 0; nt < 8; ++nt) {
                int col = nt * 16 + l16;
                ((unsigned short*)out)[(size_t)row * 128 + col] = f2b(acc[nt][r] * sc);
            }
        }
    }
}

// ---------------- aggregation: wave per node, 8-way MLP unroll ----------------
// hx is pre-scaled h' = (hW)*dinv;  out[n] = relu(dinv[n]*(sum_src h'[src] + h'[n]) + bias)
__global__ __launch_bounds__(256) void k_agg_b(const unsigned int* __restrict__ hx,  // [N][64]
                                               const unsigned short* __restrict__ csr,
                                               const int* __restrict__ offs,
                                               const float* __restrict__ dinv,
                                               const float* __restrict__ bias,
                                               unsigned int* __restrict__ out, int N) {
    int node = blockIdx.x * 4 + (threadIdx.x >> 6);
    int lane = threadIdx.x & 63;
    if (node >= N) return;
    float di = dinv[node];
    unsigned int q = hx[(size_t)node * 64 + lane];
    float acc0 = blo(q), acc1 = bhi(q);               // self term (already *dinv)
    int s0 = offs[node], s1 = offs[node + 1];
    for (int base = s0; base < s1; base += 64) {
        int nloc = min(64, s1 - base);
        int en = 0;
        if (lane < nloc) en = (int)csr[base + lane];
        int j = 0;
        for (; j + 8 <= nloc; j += 8) {
            int sid[8]; unsigned int g[8];
#pragma unroll
            for (int u = 0; u < 8; ++u) sid[u] = __shfl(en, j + u, 64);
#pragma unroll
            for (int u = 0; u < 8; ++u) g[u] = hx[(size_t)sid[u] * 64 + lane];  // 8 in flight
#pragma unroll
            for (int u = 0; u < 8; ++u) { acc0 += blo(g[u]); acc1 += bhi(g[u]); }
        }
        for (; j + 4 <= nloc; j += 4) {
            int sid[4]; unsigned int g[4];
#pragma unroll
            for (int u = 0; u < 4; ++u) sid[u] = __shfl(en, j + u, 64);
#pragma unroll
            for (int u = 0; u < 4; ++u) g[u] = hx[(size_t)sid[u] * 64 + lane];
#pragma unroll
            for (int u = 0; u < 4; ++u) { acc0 += blo(g[u]); acc1 += bhi(g[u]); }
        }
        for (; j < nloc; ++j) {
            int srcn = __shfl(en, j, 64);
            unsigned int g = hx[(size_t)srcn * 64 + lane];
            acc0 += blo(g); acc1 += bhi(g);
        }
    }
    float2 bb = *(const float2*)&bias[lane * 2];
    float v0 = fmaxf(acc0 * di + bb.x, 0.f);
    float v1 = fmaxf(acc1 * di + bb.y, 0.f);
    out[(size_t)node * 64 + lane] = pack2(v0, v1);
}

// ---------------- entity mean pool (bf16 in/out): wave per row ----------------
__global__ __launch_bounds__(256) void k_pool_b(const unsigned int* __restrict__ h,
                                                const int* __restrict__ ent,
                                                unsigned int* __restrict__ out) {
    int r = blockIdx.x * 4 + (threadIdx.x >> 6);
    int lane = threadIdx.x & 63;
    float a0 = 0.f, a1 = 0.f;
    int cnt = 0;
#pragma unroll
    for (int m = 0; m < 20; ++m) {
        int id = ent[r * 20 + m];
        if (id >= 0) {
            unsigned int q = h[(size_t)id * 64 + lane];
            a0 += blo(q); a1 += bhi(q); cnt++;
        }
    }
    float inv = 1.f / (float)max(cnt, 1);
    out[(size_t)r * 64 + lane] = pack2(a0 * inv, a1 * inv);
}

// ---------------- MLP fc1 (MFMA): z = relu([bertb|gnnb] @ fc1wt + fc1_b), z fp32
__global__ __launch_bounds__(256) void k_mlp1_mfma(const bf16_t* __restrict__ bertb,
                                                   const bf16_t* __restrict__ gnnb,
                                                   const bf16_t* __restrict__ fwt,  // [448][896]
                                                   const float* __restrict__ fb,
                                                   float* __restrict__ z) {
    __shared__ bf16_t As[64 * 136];
    __shared__ bf16_t Bs[64 * 136];
    int t = threadIdx.x;
    int wave = t >> 6, lane = t & 63, quad = lane >> 4, l16 = lane & 15;
    int r0 = blockIdx.x * 64, c0 = blockIdx.y * 64;
    facc4 acc[4];
#pragma unroll
    for (int nt = 0; nt < 4; ++nt) acc[nt] = (facc4){0.f, 0.f, 0.f, 0.f};

    for (int ks = 0; ks < 7; ++ks) {
#pragma unroll
        for (int i = 0; i < 4; ++i) {
            int chunk = t + i * 256;
            int row = chunk >> 4, c8 = (chunk & 15) << 3;
            int gr = r0 + row;
            const bf16_t* srcp = (ks < 6) ? &bertb[(size_t)gr * 768 + ks * 128 + c8]
                                          : &gnnb[(size_t)gr * 128 + c8];
            *(uint4*)&As[row * 136 + c8] = *(const uint4*)srcp;
        }
#pragma unroll
        for (int i = 0; i < 4; ++i) {
            int chunk = t + i * 256;
            int row = chunk >> 4, c8 = (chunk & 15) << 3;
            *(uint4*)&Bs[row * 136 + c8] =
                *(const uint4*)&fwt[(size_t)(c0 + row) * 896 + ks * 128 + c8];
        }
        __syncthreads();
        int arow = (wave << 4) + l16;
#pragma unroll
        for (int sub = 0; sub < 4; ++sub) {
            int kk = sub * 32 + quad * 8;
            bfrag8 af = *(const bfrag8*)&As[arow * 136 + kk];
#pragma unroll
            for (int nt = 0; nt < 4; ++nt) {
                bfrag8 bf = *(const bfrag8*)&Bs[(nt * 16 + l16) * 136 + kk];
                acc[nt] = __builtin_amdgcn_mfma_f32_16x16x32_bf16(af, bf, acc[nt], 0, 0, 0);
            }
        }
        __syncthreads();
    }
    int rbase = r0 + (wave << 4) + quad * 4;
#pragma unroll
    for (int nt = 0; nt < 4; ++nt) {
        int col = c0 + nt * 16 + l16;
        float bb = fb[col];
#pragma unroll
        for (int r = 0; r < 4; ++r)
            z[(size_t)(rbase + r) * 448 + col] = fmaxf(acc[nt][r] + bb, 0.f);
    }
}

// ---------------- MLP fc2 + sigmoid: wave per row, 4 rows/block ----------------
__global__ __launch_bounds__(256) void k_mlp2(const float* __restrict__ z,
                                              const float* __restrict__ w,
                                              const float* __restrict__ b,
                                              float* __restrict__ out) {
    int r = blockIdx.x * 4 + (threadIdx.x >> 6);
    int lane = threadIdx.x & 63;
    float acc = 0.f;
#pragma unroll
    for (int i = 0; i < 7; ++i) {
        int c = lane + i * 64;
        acc += z[(size_t)r * 448 + c] * w[c];
    }
#pragma unroll
    for (int off = 32; off > 0; off >>= 1) acc += __shfl_down(acc, off, 64);
    if (lane == 0) {
        float lg = acc + b[0];
        out[r] = 1.f / (1.f + expf(-lg));
    }
}

extern "C" void kernel_launch(void* const* d_in, const int* in_sizes, int n_in,
                              void* d_out, int out_size, void* d_ws, size_t ws_size,
                              hipStream_t stream) {
    const float* bert = (const float*)d_in[0];
    const float* x    = (const float*)d_in[1];
    const int*   ei   = (const int*)d_in[2];
    const int*   ent  = (const int*)d_in[3];
    const float* W1   = (const float*)d_in[4];
    const float* b1   = (const float*)d_in[5];
    const float* W2   = (const float*)d_in[6];
    const float* b2   = (const float*)d_in[7];
    const float* fc1w = (const float*)d_in[8];
    const float* fc1b = (const float*)d_in[9];
    const float* fc2w = (const float*)d_in[10];
    const float* fc2b = (const float*)d_in[11];
    float* out = (float*)d_out;

    const int N = in_sizes[1] / 128;   // 50000 (< 65536 required for 16-bit packing)
    const int E = in_sizes[2] / 2;     // 800000
    const int B = in_sizes[0] / 768;   // 4096

    const int* srcv = ei;
    const int* dstv = ei + E;

    char* wsp = (char*)d_ws;
    size_t off = 0;
    auto alloc = [&](size_t bytes) -> void* {
        void* p = wsp + off;
        off += (bytes + 255) & ~(size_t)255;
        return p;
    };
    float* dinv   = (float*)alloc((size_t)N * 4);
    int*   incnt  = (int*)alloc((size_t)N * 4);
    int*   offs   = (int*)alloc((size_t)(N + 1) * 4);
    int*   bsum   = (int*)alloc(256 * 4);
    int*   boff   = (int*)alloc(256 * 4);
    int*   btail  = (int*)alloc(NBUCK * 4);
    unsigned int*   ebuf  = (unsigned int*)alloc((size_t)E * 4);
    unsigned short* csr16 = (unsigned short*)alloc((size_t)E * 2);
    bf16_t* xb    = (bf16_t*)alloc((size_t)N * 128 * 2);
    bf16_t* bertb = (bf16_t*)alloc((size_t)B * 768 * 2);
    bf16_t* w1t   = (bf16_t*)alloc(128 * 128 * 2);
    bf16_t* w2t   = (bf16_t*)alloc(128 * 128 * 2);
    bf16_t* fwt   = (bf16_t*)alloc((size_t)896 * 448 * 2);
    bf16_t* gbuf  = (bf16_t*)alloc((size_t)N * 128 * 2);   // h' = (hW)*dinv
    bf16_t* hbuf  = (bf16_t*)alloc((size_t)N * 128 * 2);   // agg out (post-relu)
    bf16_t* gnnb  = (bf16_t*)alloc((size_t)B * 128 * 2);
    float* zbuf   = (float*)alloc((size_t)B * 448 * 4);
    (void)ws_size; (void)n_in; (void)out_size;

    hipMemsetAsync(incnt, 0, (size_t)N * 4, stream);

    int nb = (N + 255) / 256;
    k_count<<<(E + 255) / 256, 256, 0, stream>>>(dstv, incnt, E);
    k_dinv <<<nb, 256, 0, stream>>>(incnt, dinv, N);
    k_scan1<<<nb, 256, 0, stream>>>(incnt, offs, bsum, N);
    k_scan2<<<1, 256, 0, stream>>>(bsum, boff, nb);
    k_scan3<<<nb, 256, 0, stream>>>(offs, boff, N, E);
    k_binit<<<(NBUCK + 255) / 256, 256, 0, stream>>>(offs, btail, N);
    k_bin  <<<(E + 4095) / 4096, 256, 0, stream>>>(srcv, dstv, btail, ebuf, E, N);
    k_build<<<NBUCK, 256, 0, stream>>>(ebuf, offs, csr16, N);

    int nx8 = N * 128 / 8, nb8 = B * 768 / 8;
    k_cvt<<<(nx8 + 255) / 256, 256, 0, stream>>>(x, (unsigned int*)xb, nx8);
    k_cvt<<<(nb8 + 255) / 256, 256, 0, stream>>>(bert, (unsigned int*)bertb, nb8);
    k_prep_wt<<<(128 * 128 + 255) / 256, 256, 0, stream>>>(W1, (unsigned short*)w1t, 128, 128);
    k_prep_wt<<<(128 * 128 + 255) / 256, 256, 0, stream>>>(W2, (unsigned short*)w2t, 128, 128);
    k_prep_wt<<<(896 * 448 + 255) / 256, 256, 0, stream>>>(fc1w, (unsigned short*)fwt, 896, 448);

    int gb = (N + 63) / 64;
    k_gemm_nn128<<<gb, 256, 0, stream>>>(xb, w1t, dinv, gbuf, N);
    k_agg_b<<<(N + 3) / 4, 256, 0, stream>>>((const unsigned int*)gbuf, csr16, offs, dinv, b1,
                                             (unsigned int*)hbuf, N);
    k_gemm_nn128<<<gb, 256, 0, stream>>>(hbuf, w2t, dinv, gbuf, N);
    k_agg_b<<<(N + 3) / 4, 256, 0, stream>>>((const unsigned int*)gbuf, csr16, offs, dinv, b2,
                                             (unsigned int*)hbuf, N);
    k_pool_b<<<B / 4, 256, 0, stream>>>((const unsigned int*)hbuf, ent, (unsigned int*)gnnb);
    k_mlp1_mfma<<<dim3(B / 64, 7), 256, 0, stream>>>(bertb, gnnb, fwt, fc1b, zbuf);
    k_mlp2<<<B / 4, 256, 0, stream>>>(zbuf, fc2w, fc2b, out);
}

// Round 6
// 284.372 us; speedup vs baseline: 1.0938x; 1.0226x over previous
//
#include <hip/hip_runtime.h>
#include <math.h>

typedef __bf16 bf16_t;
typedef __bf16 bfrag8 __attribute__((ext_vector_type(8)));
typedef float  facc4  __attribute__((ext_vector_type(4)));

#define NBUCK 512   // dst-buckets for CSR multisplit (requires N < 65536 for 16-bit packing)

__device__ inline unsigned short f2b(float x) {          // RNE float->bf16 bits
    unsigned int u = __float_as_uint(x);
    unsigned int r = (u + 0x7fffu + ((u >> 16) & 1u)) >> 16;
    return (unsigned short)r;
}
__device__ inline unsigned int pack2(float lo, float hi) {
    return (unsigned int)f2b(lo) | ((unsigned int)f2b(hi) << 16);
}
__device__ inline float blo(unsigned int q) { return __uint_as_float(q << 16); }
__device__ inline float bhi(unsigned int q) { return __uint_as_float(q & 0xffff0000u); }

__device__ inline int bucket_of(int d, int N) {
    return (int)(((long long)d * NBUCK) / N);
}

// ---------------- degree count / scan (dinv fused into scan1) ----------------

__global__ void k_count(const int* __restrict__ dst, int* __restrict__ cnt, int E) {
    int e = blockIdx.x * 256 + threadIdx.x;
    if (e < E) atomicAdd(&cnt[dst[e]], 1);
}

__global__ void k_scan1(const int* __restrict__ cnt, int* __restrict__ offs,
                        int* __restrict__ bsum, float* __restrict__ dinv, int N) {
    __shared__ int sm[256];
    int t = threadIdx.x, i = blockIdx.x * 256 + t;
    int v = (i < N) ? cnt[i] : 0;
    if (i < N) dinv[i] = rsqrtf((float)(v + 1));   // +1 = self loop (fused k_dinv)
    sm[t] = v;
    __syncthreads();
    for (int off = 1; off < 256; off <<= 1) {
        int x = (t >= off) ? sm[t - off] : 0;
        __syncthreads();
        sm[t] += x;
        __syncthreads();
    }
    if (i < N) offs[i] = sm[t] - v;
    if (t == 255) bsum[blockIdx.x] = sm[255];
}

__global__ void k_scan2(const int* __restrict__ bsum, int* __restrict__ boff, int nb) {
    __shared__ int sm[256];
    int t = threadIdx.x;
    int v = (t < nb) ? bsum[t] : 0;
    sm[t] = v;
    __syncthreads();
    for (int off = 1; off < 256; off <<= 1) {
        int x = (t >= off) ? sm[t - off] : 0;
        __syncthreads();
        sm[t] += x;
        __syncthreads();
    }
    if (t < nb) boff[t] = sm[t] - v;
}

__global__ void k_scan3(int* __restrict__ offs, const int* __restrict__ boff, int N, int E) {
    int t = threadIdx.x, i = blockIdx.x * 256 + t;
    if (i < N) offs[i] += boff[blockIdx.x];
    if (blockIdx.x == 0 && t == 0) offs[N] = E;
}

// ---------------- CSR multisplit ----------------
__global__ void k_binit(const int* __restrict__ offs, int* __restrict__ btail, int N) {
    int b = blockIdx.x * 256 + threadIdx.x;
    if (b < NBUCK) btail[b] = offs[(int)(((long long)b * N + NBUCK - 1) / NBUCK)];
}

// Pass 1: LDS multisplit of 4096-edge chunks into NBUCK dst-buckets, then
// wave-coalesced run writes (scattered partial-line stores are NOT merged by
// HW: measured 64B HBM write per 8B store in rounds 3-4).
__global__ __launch_bounds__(256) void k_bin(const int* __restrict__ src,
                                             const int* __restrict__ dst,
                                             int* __restrict__ btail,
                                             unsigned int* __restrict__ ebuf,
                                             int E, int N) {
    __shared__ unsigned int sorted[4096];
    __shared__ int hist[NBUCK];      // histogram, then scatter cursor
    __shared__ int lstart[NBUCK];
    __shared__ int gbase[NBUCK];
    __shared__ int sm[256];
    int tid = threadIdx.x;
    int base = blockIdx.x * 4096;
    int cnt = min(4096, E - base);
    hist[tid] = 0; hist[tid + 256] = 0;
    __syncthreads();
    unsigned int mye[16]; int myb[16];
#pragma unroll
    for (int i = 0; i < 16; ++i) {
        int idx = i * 256 + tid;
        myb[i] = -1;
        if (idx < cnt) {
            int e = base + idx;
            int s = src[e], d = dst[e];
            mye[i] = ((unsigned int)s << 16) | (unsigned int)d;   // needs s,d < 65536
            int b = bucket_of(d, N);
            myb[i] = b;
            atomicAdd(&hist[b], 1);
        }
    }
    __syncthreads();
    int p0 = hist[2 * tid], p1 = hist[2 * tid + 1];
    sm[tid] = p0 + p1;
    __syncthreads();
    for (int off = 1; off < 256; off <<= 1) {
        int x = (tid >= off) ? sm[tid - off] : 0;
        __syncthreads();
        sm[tid] += x;
        __syncthreads();
    }
    int excl = sm[tid] - (p0 + p1);
    lstart[2 * tid] = excl;
    lstart[2 * tid + 1] = excl + p0;
    __syncthreads();
    hist[tid] = lstart[tid]; hist[tid + 256] = lstart[tid + 256];   // cursors
    __syncthreads();
#pragma unroll
    for (int i = 0; i < 16; ++i) {
        if (myb[i] >= 0) {
            int pos = atomicAdd(&hist[myb[i]], 1);
            sorted[pos] = mye[i];
        }
    }
    __syncthreads();
    for (int b = tid; b < NBUCK; b += 256) {
        int c = hist[b] - lstart[b];
        gbase[b] = (c > 0) ? atomicAdd(&btail[b], c) : 0;
    }
    __syncthreads();
    for (int idx = tid; idx < cnt; idx += 256) {
        unsigned int v = sorted[idx];
        int b = bucket_of((int)(v & 0xffffu), N);
        ebuf[gbase[b] + (idx - lstart[b])] = v;
    }
}

// Pass 2: one WG per bucket; per-node scatter inside LDS, coalesced segment out.
#define SEGCAP 16384
__global__ __launch_bounds__(256) void k_build(const unsigned int* __restrict__ ebuf,
                                               const int* __restrict__ offs,
                                               unsigned short* __restrict__ csr,
                                               int N) {
    __shared__ unsigned short seg[SEGCAP];
    __shared__ int curl[256];
    __shared__ int loff[257];
    int b = blockIdx.x, tid = threadIdx.x;
    int lo = (int)(((long long)b * N + NBUCK - 1) / NBUCK);
    int hi = (int)(((long long)(b + 1) * N + NBUCK - 1) / NBUCK);
    int nrange = hi - lo;                       // <= ceil(N/NBUCK) ~ 98
    for (int i = tid; i <= nrange; i += 256) loff[i] = offs[lo + i];
    for (int i = tid; i < nrange; i += 256) curl[i] = 0;
    __syncthreads();
    int segbase = loff[0], segend = loff[nrange];
    int cnt = segend - segbase;
    if (cnt <= SEGCAP) {
        for (int idx = segbase + tid; idx < segend; idx += 256) {
            unsigned int v = ebuf[idx];
            int d = (int)(v & 0xffffu) - lo;
            int local = atomicAdd(&curl[d], 1);
            seg[loff[d] - segbase + local] = (unsigned short)(v >> 16);
        }
        __syncthreads();
        for (int idx = tid; idx < cnt; idx += 256)
            csr[segbase + idx] = seg[idx];
    } else {
        for (int idx = segbase + tid; idx < segend; idx += 256) {
            unsigned int v = ebuf[idx];
            int d = (int)(v & 0xffffu) - lo;
            int local = atomicAdd(&curl[d], 1);
            csr[loff[d] + local] = (unsigned short)(v >> 16);
        }
    }
}

// ---------------- fused fp32->bf16 convert for x and bert ----------------
__global__ void k_cvt2(const float* __restrict__ inA, unsigned int* __restrict__ outA, int n8A,
                       const float* __restrict__ inB, unsigned int* __restrict__ outB, int n8B) {
    int i = blockIdx.x * 256 + threadIdx.x;
    const float* in; unsigned int* ob; int idx;
    if (i < n8A) { in = inA; ob = outA; idx = i; }
    else if (i < n8A + n8B) { in = inB; ob = outB; idx = i - n8A; }
    else return;
    const float4* p = (const float4*)in + (size_t)idx * 2;
    float4 a = p[0], b = p[1];
    uint4 o;
    o.x = pack2(a.x, a.y);
    o.y = pack2(a.z, a.w);
    o.z = pack2(b.x, b.y);
    o.w = pack2(b.z, b.w);
    ((uint4*)ob)[idx] = o;
}

// ---------------- fused weight transpose+cvt for W1, W2, fc1w ----------------
__global__ void k_prepw(const float* __restrict__ W1, unsigned short* __restrict__ w1t,
                        const float* __restrict__ W2, unsigned short* __restrict__ w2t,
                        const float* __restrict__ Wf, unsigned short* __restrict__ fwt) {
    int i = blockIdx.x * 256 + threadIdx.x;
    const float* W; unsigned short* Wt; int K, Nn, idx;
    if (i < 16384)      { W = W1; Wt = w1t; K = 128; Nn = 128; idx = i; }
    else if (i < 32768) { W = W2; Wt = w2t; K = 128; Nn = 128; idx = i - 16384; }
    else if (i < 32768 + 896 * 448) { W = Wf; Wt = fwt; K = 896; Nn = 448; idx = i - 32768; }
    else return;
    int n = idx / K, k = idx - n * K;
    Wt[idx] = f2b(W[(size_t)k * Nn + n]);
}

// ---------------- MFMA GEMM: out[m] = (A @ Bt^T)[m] * rs[m]  (bf16 out) --------
__global__ __launch_bounds__(256) void k_gemm_nn128(const bf16_t* __restrict__ A,
                                                    const bf16_t* __restrict__ Bt,
                                                    const float* __restrict__ rs,
                                                    bf16_t* __restrict__ out, int M) {
    __shared__ bf16_t As[64 * 136];
    __shared__ bf16_t Bs[128 * 136];
    int t = threadIdx.x;
    int wave = t >> 6, lane = t & 63, quad = lane >> 4, l16 = lane & 15;
    int r0 = blockIdx.x * 64;
#pragma unroll
    for (int i = 0; i < 4; ++i) {
        int chunk = t + i * 256;
        int row = chunk >> 4, c8 = (chunk & 15) << 3;
        int gr = r0 + row;
        uint4 v = make_uint4(0u, 0u, 0u, 0u);
        if (gr < M) v = *(const uint4*)&A[(size_t)gr * 128 + c8];
        *(uint4*)&As[row * 136 + c8] = v;
    }
#pragma unroll
    for (int i = 0; i < 8; ++i) {
        int chunk = t + i * 256;
        int row = chunk >> 4, c8 = (chunk & 15) << 3;
        *(uint4*)&Bs[row * 136 + c8] = *(const uint4*)&Bt[row * 128 + c8];
    }
    __syncthreads();

    facc4 acc[8];
#pragma unroll
    for (int nt = 0; nt < 8; ++nt) acc[nt] = (facc4){0.f, 0.f, 0.f, 0.f};
    int arow = (wave << 4) + l16;
#pragma unroll
    for (int ks = 0; ks < 4; ++ks) {
        int kk = ks * 32 + quad * 8;
        bfrag8 af = *(const bfrag8*)&As[arow * 136 + kk];
#pragma unroll
        for (int nt = 0; nt < 8; ++nt) {
            bfrag8 bf = *(const bfrag8*)&Bs[(nt * 16 + l16) * 136 + kk];
            acc[nt] = __builtin_amdgcn_mfma_f32_16x16x32_bf16(af, bf, acc[nt], 0, 0, 0);
        }
    }
    int rbase = r0 + (wave << 4) + quad * 4;
#pragma unroll
    for (int r = 0; r < 4; ++r) {
        int row = rbase + r;
        if (row < M) {
            float sc = rs[row];
#pragma unroll
            for (int nt = 0; nt < 8; ++nt) {
                int col = nt * 16 + l16;
                ((unsigned short*)out)[(size_t)row * 128 + col] = f2b(acc[nt][r] * sc);
            }
        }
    }
}

// ---------------- aggregation: wave per node, 16-deep gather batch ----------------
// hx is pre-scaled h' = (hW)*dinv;  out[n] = relu(dinv[n]*(sum_src h'[src] + h'[n]) + bias)
__global__ __launch_bounds__(256) void k_agg_b(const unsigned int* __restrict__ hx,  // [N][64]
                                               const unsigned short* __restrict__ csr,
                                               const int* __restrict__ offs,
                                               const float* __restrict__ dinv,
                                               const float* __restrict__ bias,
                                               unsigned int* __restrict__ out, int N) {
    int node = blockIdx.x * 4 + (threadIdx.x >> 6);
    int lane = threadIdx.x & 63;
    if (node >= N) return;
    float di = dinv[node];
    unsigned int q = hx[(size_t)node * 64 + lane];
    float acc0 = blo(q), acc1 = bhi(q);               // self term (already *dinv)
    int s0 = offs[node], s1 = offs[node + 1];
    for (int base = s0; base < s1; base += 64) {
        int nloc = min(64, s1 - base);
        int en = 0;
        if (lane < nloc) en = (int)csr[base + lane];
        int j = 0;
        for (; j + 16 <= nloc; j += 16) {
            int sid[16]; unsigned int g[16];
#pragma unroll
            for (int u = 0; u < 16; ++u) sid[u] = __shfl(en, j + u, 64);
#pragma unroll
            for (int u = 0; u < 16; ++u) g[u] = hx[(size_t)sid[u] * 64 + lane];  // 16 in flight
#pragma unroll
            for (int u = 0; u < 16; ++u) { acc0 += blo(g[u]); acc1 += bhi(g[u]); }
        }
        for (; j + 4 <= nloc; j += 4) {
            int sid[4]; unsigned int g[4];
#pragma unroll
            for (int u = 0; u < 4; ++u) sid[u] = __shfl(en, j + u, 64);
#pragma unroll
            for (int u = 0; u < 4; ++u) g[u] = hx[(size_t)sid[u] * 64 + lane];
#pragma unroll
            for (int u = 0; u < 4; ++u) { acc0 += blo(g[u]); acc1 += bhi(g[u]); }
        }
        for (; j < nloc; ++j) {
            int srcn = __shfl(en, j, 64);
            unsigned int g = hx[(size_t)srcn * 64 + lane];
            acc0 += blo(g); acc1 += bhi(g);
        }
    }
    float2 bb = *(const float2*)&bias[lane * 2];
    float v0 = fmaxf(acc0 * di + bb.x, 0.f);
    float v1 = fmaxf(acc1 * di + bb.y, 0.f);
    out[(size_t)node * 64 + lane] = pack2(v0, v1);
}

// ---------------- entity mean pool (bf16 in/out): wave per row ----------------
__global__ __launch_bounds__(256) void k_pool_b(const unsigned int* __restrict__ h,
                                                const int* __restrict__ ent,
                                                unsigned int* __restrict__ out) {
    int r = blockIdx.x * 4 + (threadIdx.x >> 6);
    int lane = threadIdx.x & 63;
    float a0 = 0.f, a1 = 0.f;
    int cnt = 0;
#pragma unroll
    for (int m = 0; m < 20; ++m) {
        int id = ent[r * 20 + m];
        if (id >= 0) {
            unsigned int q = h[(size_t)id * 64 + lane];
            a0 += blo(q); a1 += bhi(q); cnt++;
        }
    }
    float inv = 1.f / (float)max(cnt, 1);
    out[(size_t)r * 64 + lane] = pack2(a0 * inv, a1 * inv);
}

// ---------------- MLP fc1 (MFMA): z = relu([bertb|gnnb] @ fc1wt + fc1_b), z fp32
__global__ __launch_bounds__(256) void k_mlp1_mfma(const bf16_t* __restrict__ bertb,
                                                   const bf16_t* __restrict__ gnnb,
                                                   const bf16_t* __restrict__ fwt,  // [448][896]
                                                   const float* __restrict__ fb,
                                                   float* __restrict__ z) {
    __shared__ bf16_t As[64 * 136];
    __shared__ bf16_t Bs[64 * 136];
    int t = threadIdx.x;
    int wave = t >> 6, lane = t & 63, quad = lane >> 4, l16 = lane & 15;
    int r0 = blockIdx.x * 64, c0 = blockIdx.y * 64;
    facc4 acc[4];
#pragma unroll
    for (int nt = 0; nt < 4; ++nt) acc[nt] = (facc4){0.f, 0.f, 0.f, 0.f};

    for (int ks = 0; ks < 7; ++ks) {
#pragma unroll
        for (int i = 0; i < 4; ++i) {
            int chunk = t + i * 256;
            int row = chunk >> 4, c8 = (chunk & 15) << 3;
            int gr = r0 + row;
            const bf16_t* srcp = (ks < 6) ? &bertb[(size_t)gr * 768 + ks * 128 + c8]
                                          : &gnnb[(size_t)gr * 128 + c8];
            *(uint4*)&As[row * 136 + c8] = *(const uint4*)srcp;
        }
#pragma unroll
        for (int i = 0; i < 4; ++i) {
            int chunk = t + i * 256;
            int row = chunk >> 4, c8 = (chunk & 15) << 3;
            *(uint4*)&Bs[row * 136 + c8] =
                *(const uint4*)&fwt[(size_t)(c0 + row) * 896 + ks * 128 + c8];
        }
        __syncthreads();
        int arow = (wave << 4) + l16;
#pragma unroll
        for (int sub = 0; sub < 4; ++sub) {
            int kk = sub * 32 + quad * 8;
            bfrag8 af = *(const bfrag8*)&As[arow * 136 + kk];
#pragma unroll
            for (int nt = 0; nt < 4; ++nt) {
                bfrag8 bf = *(const bfrag8*)&Bs[(nt * 16 + l16) * 136 + kk];
                acc[nt] = __builtin_amdgcn_mfma_f32_16x16x32_bf16(af, bf, acc[nt], 0, 0, 0);
            }
        }
        __syncthreads();
    }
    int rbase = r0 + (wave << 4) + quad * 4;
#pragma unroll
    for (int nt = 0; nt < 4; ++nt) {
        int col = c0 + nt * 16 + l16;
        float bb = fb[col];
#pragma unroll
        for (int r = 0; r < 4; ++r)
            z[(size_t)(rbase + r) * 448 + col] = fmaxf(acc[nt][r] + bb, 0.f);
    }
}

// ---------------- MLP fc2 + sigmoid: wave per row, 4 rows/block ----------------
__global__ __launch_bounds__(256) void k_mlp2(const float* __restrict__ z,
                                              const float* __restrict__ w,
                                              const float* __restrict__ b,
                                              float* __restrict__ out) {
    int r = blockIdx.x * 4 + (threadIdx.x >> 6);
    int lane = threadIdx.x & 63;
    float acc = 0.f;
#pragma unroll
    for (int i = 0; i < 7; ++i) {
        int c = lane + i * 64;
        acc += z[(size_t)r * 448 + c] * w[c];
    }
#pragma unroll
    for (int off = 32; off > 0; off >>= 1) acc += __shfl_down(acc, off, 64);
    if (lane == 0) {
        float lg = acc + b[0];
        out[r] = 1.f / (1.f + expf(-lg));
    }
}

extern "C" void kernel_launch(void* const* d_in, const int* in_sizes, int n_in,
                              void* d_out, int out_size, void* d_ws, size_t ws_size,
                              hipStream_t stream) {
    const float* bert = (const float*)d_in[0];
    const float* x    = (const float*)d_in[1];
    const int*   ei   = (const int*)d_in[2];
    const int*   ent  = (const int*)d_in[3];
    const float* W1   = (const float*)d_in[4];
    const float* b1   = (const float*)d_in[5];
    const float* W2   = (const float*)d_in[6];
    const float* b2   = (const float*)d_in[7];
    const float* fc1w = (const float*)d_in[8];
    const float* fc1b = (const float*)d_in[9];
    const float* fc2w = (const float*)d_in[10];
    const float* fc2b = (const float*)d_in[11];
    float* out = (float*)d_out;

    const int N = in_sizes[1] / 128;   // 50000 (< 65536 required for 16-bit packing)
    const int E = in_sizes[2] / 2;     // 800000
    const int B = in_sizes[0] / 768;   // 4096

    const int* srcv = ei;
    const int* dstv = ei + E;

    char* wsp = (char*)d_ws;
    size_t off = 0;
    auto alloc = [&](size_t bytes) -> void* {
        void* p = wsp + off;
        off += (bytes + 255) & ~(size_t)255;
        return p;
    };
    float* dinv   = (float*)alloc((size_t)N * 4);
    int*   incnt  = (int*)alloc((size_t)N * 4);
    int*   offs   = (int*)alloc((size_t)(N + 1) * 4);
    int*   bsum   = (int*)alloc(256 * 4);
    int*   boff   = (int*)alloc(256 * 4);
    int*   btail  = (int*)alloc(NBUCK * 4);
    unsigned int*   ebuf  = (unsigned int*)alloc((size_t)E * 4);
    unsigned short* csr16 = (unsigned short*)alloc((size_t)E * 2);
    bf16_t* xb    = (bf16_t*)alloc((size_t)N * 128 * 2);
    bf16_t* bertb = (bf16_t*)alloc((size_t)B * 768 * 2);
    bf16_t* w1t   = (bf16_t*)alloc(128 * 128 * 2);
    bf16_t* w2t   = (bf16_t*)alloc(128 * 128 * 2);
    bf16_t* fwt   = (bf16_t*)alloc((size_t)896 * 448 * 2);
    bf16_t* gbuf  = (bf16_t*)alloc((size_t)N * 128 * 2);   // h' = (hW)*dinv
    bf16_t* hbuf  = (bf16_t*)alloc((size_t)N * 128 * 2);   // agg out (post-relu)
    bf16_t* gnnb  = (bf16_t*)alloc((size_t)B * 128 * 2);
    float* zbuf   = (float*)alloc((size_t)B * 448 * 4);
    (void)ws_size; (void)n_in; (void)out_size;

    hipMemsetAsync(incnt, 0, (size_t)N * 4, stream);

    int nb = (N + 255) / 256;
    k_count<<<(E + 255) / 256, 256, 0, stream>>>(dstv, incnt, E);
    k_scan1<<<nb, 256, 0, stream>>>(incnt, offs, bsum, dinv, N);
    k_scan2<<<1, 256, 0, stream>>>(bsum, boff, nb);
    k_scan3<<<nb, 256, 0, stream>>>(offs, boff, N, E);
    k_binit<<<(NBUCK + 255) / 256, 256, 0, stream>>>(offs, btail, N);
    k_bin  <<<(E + 4095) / 4096, 256, 0, stream>>>(srcv, dstv, btail, ebuf, E, N);
    k_build<<<NBUCK, 256, 0, stream>>>(ebuf, offs, csr16, N);

    int nx8 = N * 128 / 8, nb8 = B * 768 / 8;
    k_cvt2<<<(nx8 + nb8 + 255) / 256, 256, 0, stream>>>(x, (unsigned int*)xb, nx8,
                                                        bert, (unsigned int*)bertb, nb8);
    int prepn = 16384 + 16384 + 896 * 448;
    k_prepw<<<(prepn + 255) / 256, 256, 0, stream>>>(W1, (unsigned short*)w1t,
                                                     W2, (unsigned short*)w2t,
                                                     fc1w, (unsigned short*)fwt);

    int gb = (N + 63) / 64;
    k_gemm_nn128<<<gb, 256, 0, stream>>>(xb, w1t, dinv, gbuf, N);
    k_agg_b<<<(N + 3) / 4, 256, 0, stream>>>((const unsigned int*)gbuf, csr16, offs, dinv, b1,
                                             (unsigned int*)hbuf, N);
    k_gemm_nn128<<<gb, 256, 0, stream>>>(hbuf, w2t, dinv, gbuf, N);
    k_agg_b<<<(N + 3) / 4, 256, 0, stream>>>((const unsigned int*)gbuf, csr16, offs, dinv, b2,
                                             (unsigned int*)hbuf, N);
    k_pool_b<<<B / 4, 256, 0, stream>>>((const unsigned int*)hbuf, ent, (unsigned int*)gnnb);
    k_mlp1_mfma<<<dim3(B / 64, 7), 256, 0, stream>>>(bertb, gnnb, fwt, fc1b, zbuf);
    k_mlp2<<<B / 4, 256, 0, stream>>>(zbuf, fc2w, fc2b, out);
}

// Round 7
// 237.704 us; speedup vs baseline: 1.3086x; 1.1963x over previous
//
#include <hip/hip_runtime.h>
#include <math.h>

typedef __bf16 bf16_t;
typedef __bf16 bfrag8 __attribute__((ext_vector_type(8)));
typedef float  facc4  __attribute__((ext_vector_type(4)));

#define NBUCK 512   // dst-buckets for CSR multisplit (requires N < 65536 for 16-bit packing)
#define BCAP  4096  // per-bucket ebuf capacity (mean 1568, sd ~40 -> 4096 is ~64 sd)

__device__ inline unsigned short f2b(float x) {          // RNE float->bf16 bits
    unsigned int u = __float_as_uint(x);
    unsigned int r = (u + 0x7fffu + ((u >> 16) & 1u)) >> 16;
    return (unsigned short)r;
}
__device__ inline unsigned int pack2(float lo, float hi) {
    return (unsigned int)f2b(lo) | ((unsigned int)f2b(hi) << 16);
}
__device__ inline float blo(unsigned int q) { return __uint_as_float(q << 16); }
__device__ inline float bhi(unsigned int q) { return __uint_as_float(q & 0xffff0000u); }

__device__ inline int bucket_of(int d, int N) {
    return (int)(((long long)d * NBUCK) / N);
}

// ---------------- CSR build, pass 1: LDS multisplit into per-bucket ebuf regions.
// Bucket totals (bcnt) come out as a byproduct of the region reservation.
__global__ __launch_bounds__(256) void k_bin2(const int* __restrict__ src,
                                              const int* __restrict__ dst,
                                              int* __restrict__ bcnt,
                                              unsigned int* __restrict__ ebuf,
                                              int E, int N) {
    __shared__ unsigned int sorted[4096];
    __shared__ int hist[NBUCK];      // histogram, then scatter cursor
    __shared__ int lstart[NBUCK];
    __shared__ int gbase[NBUCK];
    __shared__ int sm[256];
    int tid = threadIdx.x;
    int base = blockIdx.x * 4096;
    int cnt = min(4096, E - base);
    hist[tid] = 0; hist[tid + 256] = 0;
    __syncthreads();
    unsigned int mye[16]; int myb[16];
#pragma unroll
    for (int i = 0; i < 16; ++i) {
        int idx = i * 256 + tid;
        myb[i] = -1;
        if (idx < cnt) {
            int e = base + idx;
            int s = src[e], d = dst[e];
            mye[i] = ((unsigned int)s << 16) | (unsigned int)d;   // needs s,d < 65536
            int b = bucket_of(d, N);
            myb[i] = b;
            atomicAdd(&hist[b], 1);
        }
    }
    __syncthreads();
    int p0 = hist[2 * tid], p1 = hist[2 * tid + 1];
    sm[tid] = p0 + p1;
    __syncthreads();
    for (int off = 1; off < 256; off <<= 1) {
        int x = (tid >= off) ? sm[tid - off] : 0;
        __syncthreads();
        sm[tid] += x;
        __syncthreads();
    }
    int excl = sm[tid] - (p0 + p1);
    lstart[2 * tid] = excl;
    lstart[2 * tid + 1] = excl + p0;
    __syncthreads();
    hist[tid] = lstart[tid]; hist[tid + 256] = lstart[tid + 256];   // cursors
    __syncthreads();
#pragma unroll
    for (int i = 0; i < 16; ++i) {
        if (myb[i] >= 0) {
            int pos = atomicAdd(&hist[myb[i]], 1);
            sorted[pos] = mye[i];
        }
    }
    __syncthreads();
    for (int b = tid; b < NBUCK; b += 256) {
        int c = hist[b] - lstart[b];
        gbase[b] = (c > 0) ? atomicAdd(&bcnt[b], c) : 0;
    }
    __syncthreads();
    for (int idx = tid; idx < cnt; idx += 256) {   // coalesced run writes per bucket
        unsigned int v = sorted[idx];
        int b = bucket_of((int)(v & 0xffffu), N);
        ebuf[(size_t)b * BCAP + gbase[b] + (idx - lstart[b])] = v;
    }
}

// ---------------- pass 2: scan 512 bucket totals -> global CSR bucket starts ----
__global__ void k_bscan(const int* __restrict__ bcnt, int* __restrict__ bstart,
                        int* __restrict__ offs, int N, int E) {
    __shared__ int sm[256];
    int t = threadIdx.x;
    int v0 = bcnt[2 * t], v1 = bcnt[2 * t + 1];
    sm[t] = v0 + v1;
    __syncthreads();
    for (int off = 1; off < 256; off <<= 1) {
        int x = (t >= off) ? sm[t - off] : 0;
        __syncthreads();
        sm[t] += x;
        __syncthreads();
    }
    int excl = sm[t] - (v0 + v1);
    bstart[2 * t] = excl;
    bstart[2 * t + 1] = excl + v0;
    if (t == 0) offs[N] = E;
}

// ---------------- pass 3: per-bucket node counts/offsets/dinv in LDS, coalesced CSR out.
__global__ __launch_bounds__(256) void k_build2(const unsigned int* __restrict__ ebuf,
                                                const int* __restrict__ bcnt,
                                                const int* __restrict__ bstart,
                                                int* __restrict__ offs,
                                                float* __restrict__ dinv,
                                                unsigned short* __restrict__ csr, int N) {
    __shared__ unsigned short seg[BCAP];
    __shared__ int cnt_l[128];
    __shared__ int scan_l[128];
    __shared__ int curs[128];
    int b = blockIdx.x, tid = threadIdx.x;
    int lo = (int)(((long long)b * N + NBUCK - 1) / NBUCK);
    int cnt = bcnt[b];
    int base = bstart[b];
    int nrange = (int)(((long long)(b + 1) * N + NBUCK - 1) / NBUCK) - lo;   // <= 98
    if (tid < 128) cnt_l[tid] = 0;
    __syncthreads();
    for (int i = tid; i < cnt; i += 256) {
        unsigned int v = ebuf[(size_t)b * BCAP + i];
        atomicAdd(&cnt_l[(int)(v & 0xffffu) - lo], 1);
    }
    __syncthreads();
    if (tid < 128) scan_l[tid] = cnt_l[tid];
    __syncthreads();
    for (int off = 1; off < 128; off <<= 1) {
        int x = 0;
        if (tid < 128 && tid >= off) x = scan_l[tid - off];
        __syncthreads();
        if (tid < 128) scan_l[tid] += x;
        __syncthreads();
    }
    if (tid < 128) {
        int excl = scan_l[tid] - cnt_l[tid];
        curs[tid] = excl;
        if (tid < nrange) {
            offs[lo + tid] = base + excl;
            dinv[lo + tid] = rsqrtf((float)(cnt_l[tid] + 1));   // +1 = self loop
        }
    }
    __syncthreads();
    for (int i = tid; i < cnt; i += 256) {
        unsigned int v = ebuf[(size_t)b * BCAP + i];
        int d = (int)(v & 0xffffu) - lo;
        int p = atomicAdd(&curs[d], 1);
        seg[p] = (unsigned short)(v >> 16);
    }
    __syncthreads();
    for (int i = tid; i < cnt; i += 256) csr[base + i] = seg[i];
}

// ---------------- fp32 -> bf16 conversion (bert only; x fused into gemm1) -------
__global__ void k_cvt(const float* __restrict__ in, unsigned int* __restrict__ outb, int n8) {
    int i = blockIdx.x * 256 + threadIdx.x;
    if (i >= n8) return;
    const float4* p = (const float4*)in + (size_t)i * 2;
    float4 a = p[0], b = p[1];
    uint4 o;
    o.x = pack2(a.x, a.y);
    o.y = pack2(a.z, a.w);
    o.z = pack2(b.x, b.y);
    o.w = pack2(b.z, b.w);
    ((uint4*)outb)[i] = o;
}

// ---------------- small weight transpose+cvt for W1, W2 (64KB each, naive ok) ---
__global__ void k_prepw_s(const float* __restrict__ W1, unsigned short* __restrict__ w1t,
                          const float* __restrict__ W2, unsigned short* __restrict__ w2t) {
    int i = blockIdx.x * 256 + threadIdx.x;
    if (i >= 32768) return;
    const float* W = (i < 16384) ? W1 : W2;
    unsigned short* Wt = (i < 16384) ? w1t : w2t;
    int idx = i & 16383;
    int n = idx >> 7, k = idx & 127;
    Wt[idx] = f2b(W[k * 128 + n]);
}

// ---------------- tiled transpose+cvt for fc1w: coalesced read AND write --------
// fwt[n][k] = bf16(Wf[k][n]); K=896, Nn=448. grid (Nn/64, K/64), float[64][65] tile.
__global__ __launch_bounds__(256) void k_tpose(const float* __restrict__ Wf,
                                               unsigned short* __restrict__ fwt) {
    __shared__ float tile[64][65];
    int n0 = blockIdx.x * 64, k0 = blockIdx.y * 64;
#pragma unroll
    for (int i = 0; i < 16; ++i) {
        int idx = i * 256 + threadIdx.x;
        int r = idx >> 6, c = idx & 63;                 // consecutive c -> coalesced
        tile[r][c] = Wf[(size_t)(k0 + r) * 448 + n0 + c];
    }
    __syncthreads();
#pragma unroll
    for (int i = 0; i < 16; ++i) {
        int idx = i * 256 + threadIdx.x;
        int c = idx >> 6, r = idx & 63;                 // consecutive r -> coalesced
        fwt[(size_t)(n0 + c) * 896 + k0 + r] = f2b(tile[r][c]);
    }
}

// ---------------- MFMA GEMM (fp32 A, inline cvt): out = (A @ Bt^T) * rs --------
__global__ __launch_bounds__(256) void k_gemm_f32a(const float* __restrict__ A,
                                                   const bf16_t* __restrict__ Bt,
                                                   const float* __restrict__ rs,
                                                   bf16_t* __restrict__ out, int M) {
    __shared__ bf16_t As[64 * 136];
    __shared__ bf16_t Bs[128 * 136];
    int t = threadIdx.x;
    int wave = t >> 6, lane = t & 63, quad = lane >> 4, l16 = lane & 15;
    int r0 = blockIdx.x * 64;
#pragma unroll
    for (int i = 0; i < 4; ++i) {
        int chunk = t + i * 256;
        int row = chunk >> 4, c8 = (chunk & 15) << 3;
        int gr = r0 + row;
        float4 a0 = make_float4(0.f, 0.f, 0.f, 0.f), a1 = a0;
        if (gr < M) {
            a0 = *(const float4*)&A[(size_t)gr * 128 + c8];
            a1 = *(const float4*)&A[(size_t)gr * 128 + c8 + 4];
        }
        *(uint4*)&As[row * 136 + c8] =
            make_uint4(pack2(a0.x, a0.y), pack2(a0.z, a0.w),
                       pack2(a1.x, a1.y), pack2(a1.z, a1.w));
    }
#pragma unroll
    for (int i = 0; i < 8; ++i) {
        int chunk = t + i * 256;
        int row = chunk >> 4, c8 = (chunk & 15) << 3;
        *(uint4*)&Bs[row * 136 + c8] = *(const uint4*)&Bt[row * 128 + c8];
    }
    __syncthreads();

    facc4 acc[8];
#pragma unroll
    for (int nt = 0; nt < 8; ++nt) acc[nt] = (facc4){0.f, 0.f, 0.f, 0.f};
    int arow = (wave << 4) + l16;
#pragma unroll
    for (int ks = 0; ks < 4; ++ks) {
        int kk = ks * 32 + quad * 8;
        bfrag8 af = *(const bfrag8*)&As[arow * 136 + kk];
#pragma unroll
        for (int nt = 0; nt < 8; ++nt) {
            bfrag8 bf = *(const bfrag8*)&Bs[(nt * 16 + l16) * 136 + kk];
            acc[nt] = __builtin_amdgcn_mfma_f32_16x16x32_bf16(af, bf, acc[nt], 0, 0, 0);
        }
    }
    int rbase = r0 + (wave << 4) + quad * 4;
#pragma unroll
    for (int r = 0; r < 4; ++r) {
        int row = rbase + r;
        if (row < M) {
            float sc = rs[row];
#pragma unroll
            for (int nt = 0; nt < 8; ++nt) {
                int col = nt * 16 + l16;
                ((unsigned short*)out)[(size_t)row * 128 + col] = f2b(acc[nt][r] * sc);
            }
        }
    }
}

// ---------------- MFMA GEMM (bf16 A): out = (A @ Bt^T) * rs  (layer 2) ----------
__global__ __launch_bounds__(256) void k_gemm_nn128(const bf16_t* __restrict__ A,
                                                    const bf16_t* __restrict__ Bt,
                                                    const float* __restrict__ rs,
                                                    bf16_t* __restrict__ out, int M) {
    __shared__ bf16_t As[64 * 136];
    __shared__ bf16_t Bs[128 * 136];
    int t = threadIdx.x;
    int wave = t >> 6, lane = t & 63, quad = lane >> 4, l16 = lane & 15;
    int r0 = blockIdx.x * 64;
#pragma unroll
    for (int i = 0; i < 4; ++i) {
        int chunk = t + i * 256;
        int row = chunk >> 4, c8 = (chunk & 15) << 3;
        int gr = r0 + row;
        uint4 v = make_uint4(0u, 0u, 0u, 0u);
        if (gr < M) v = *(const uint4*)&A[(size_t)gr * 128 + c8];
        *(uint4*)&As[row * 136 + c8] = v;
    }
#pragma unroll
    for (int i = 0; i < 8; ++i) {
        int chunk = t + i * 256;
        int row = chunk >> 4, c8 = (chunk & 15) << 3;
        *(uint4*)&Bs[row * 136 + c8] = *(const uint4*)&Bt[row * 128 + c8];
    }
    __syncthreads();

    facc4 acc[8];
#pragma unroll
    for (int nt = 0; nt < 8; ++nt) acc[nt] = (facc4){0.f, 0.f, 0.f, 0.f};
    int arow = (wave << 4) + l16;
#pragma unroll
    for (int ks = 0; ks < 4; ++ks) {
        int kk = ks * 32 + quad * 8;
        bfrag8 af = *(const bfrag8*)&As[arow * 136 + kk];
#pragma unroll
        for (int nt = 0; nt < 8; ++nt) {
            bfrag8 bf = *(const bfrag8*)&Bs[(nt * 16 + l16) * 136 + kk];
            acc[nt] = __builtin_amdgcn_mfma_f32_16x16x32_bf16(af, bf, acc[nt], 0, 0, 0);
        }
    }
    int rbase = r0 + (wave << 4) + quad * 4;
#pragma unroll
    for (int r = 0; r < 4; ++r) {
        int row = rbase + r;
        if (row < M) {
            float sc = rs[row];
#pragma unroll
            for (int nt = 0; nt < 8; ++nt) {
                int col = nt * 16 + l16;
                ((unsigned short*)out)[(size_t)row * 128 + col] = f2b(acc[nt][r] * sc);
            }
        }
    }
}

// ---------------- aggregation: wave per node, 16-deep gather batch ----------------
// hx is pre-scaled h' = (hW)*dinv;  out[n] = relu(dinv[n]*(sum_src h'[src] + h'[n]) + bias)
__global__ __launch_bounds__(256) void k_agg_b(const unsigned int* __restrict__ hx,  // [N][64]
                                               const unsigned short* __restrict__ csr,
                                               const int* __restrict__ offs,
                                               const float* __restrict__ dinv,
                                               const float* __restrict__ bias,
                                               unsigned int* __restrict__ out, int N) {
    int node = blockIdx.x * 4 + (threadIdx.x >> 6);
    int lane = threadIdx.x & 63;
    if (node >= N) return;
    float di = dinv[node];
    unsigned int q = hx[(size_t)node * 64 + lane];
    float acc0 = blo(q), acc1 = bhi(q);               // self term (already *dinv)
    int s0 = offs[node], s1 = offs[node + 1];
    for (int base = s0; base < s1; base += 64) {
        int nloc = min(64, s1 - base);
        int en = 0;
        if (lane < nloc) en = (int)csr[base + lane];
        int j = 0;
        for (; j + 16 <= nloc; j += 16) {
            int sid[16]; unsigned int g[16];
#pragma unroll
            for (int u = 0; u < 16; ++u) sid[u] = __shfl(en, j + u, 64);
#pragma unroll
            for (int u = 0; u < 16; ++u) g[u] = hx[(size_t)sid[u] * 64 + lane];  // 16 in flight
#pragma unroll
            for (int u = 0; u < 16; ++u) { acc0 += blo(g[u]); acc1 += bhi(g[u]); }
        }
        for (; j + 4 <= nloc; j += 4) {
            int sid[4]; unsigned int g[4];
#pragma unroll
            for (int u = 0; u < 4; ++u) sid[u] = __shfl(en, j + u, 64);
#pragma unroll
            for (int u = 0; u < 4; ++u) g[u] = hx[(size_t)sid[u] * 64 + lane];
#pragma unroll
            for (int u = 0; u < 4; ++u) { acc0 += blo(g[u]); acc1 += bhi(g[u]); }
        }
        for (; j < nloc; ++j) {
            int srcn = __shfl(en, j, 64);
            unsigned int g = hx[(size_t)srcn * 64 + lane];
            acc0 += blo(g); acc1 += bhi(g);
        }
    }
    float2 bb = *(const float2*)&bias[lane * 2];
    float v0 = fmaxf(acc0 * di + bb.x, 0.f);
    float v1 = fmaxf(acc1 * di + bb.y, 0.f);
    out[(size_t)node * 64 + lane] = pack2(v0, v1);
}

// ---------------- entity mean pool (bf16 in/out): wave per row ----------------
__global__ __launch_bounds__(256) void k_pool_b(const unsigned int* __restrict__ h,
                                                const int* __restrict__ ent,
                                                unsigned int* __restrict__ out) {
    int r = blockIdx.x * 4 + (threadIdx.x >> 6);
    int lane = threadIdx.x & 63;
    float a0 = 0.f, a1 = 0.f;
    int cnt = 0;
#pragma unroll
    for (int m = 0; m < 20; ++m) {
        int id = ent[r * 20 + m];
        if (id >= 0) {
            unsigned int q = h[(size_t)id * 64 + lane];
            a0 += blo(q); a1 += bhi(q); cnt++;
        }
    }
    float inv = 1.f / (float)max(cnt, 1);
    out[(size_t)r * 64 + lane] = pack2(a0 * inv, a1 * inv);
}

// ---------------- MLP fc1 (MFMA): z = relu([bertb|gnnb] @ fc1wt + fc1_b), z fp32
__global__ __launch_bounds__(256) void k_mlp1_mfma(const bf16_t* __restrict__ bertb,
                                                   const bf16_t* __restrict__ gnnb,
                                                   const bf16_t* __restrict__ fwt,  // [448][896]
                                                   const float* __restrict__ fb,
                                                   float* __restrict__ z) {
    __shared__ bf16_t As[64 * 136];
    __shared__ bf16_t Bs[64 * 136];
    int t = threadIdx.x;
    int wave = t >> 6, lane = t & 63, quad = lane >> 4, l16 = lane & 15;
    int r0 = blockIdx.x * 64, c0 = blockIdx.y * 64;
    facc4 acc[4];
#pragma unroll
    for (int nt = 0; nt < 4; ++nt) acc[nt] = (facc4){0.f, 0.f, 0.f, 0.f};

    for (int ks = 0; ks < 7; ++ks) {
#pragma unroll
        for (int i = 0; i < 4; ++i) {
            int chunk = t + i * 256;
            int row = chunk >> 4, c8 = (chunk & 15) << 3;
            int gr = r0 + row;
            const bf16_t* srcp = (ks < 6) ? &bertb[(size_t)gr * 768 + ks * 128 + c8]
                                          : &gnnb[(size_t)gr * 128 + c8];
            *(uint4*)&As[row * 136 + c8] = *(const uint4*)srcp;
        }
#pragma unroll
        for (int i = 0; i < 4; ++i) {
            int chunk = t + i * 256;
            int row = chunk >> 4, c8 = (chunk & 15) << 3;
            *(uint4*)&Bs[row * 136 + c8] =
                *(const uint4*)&fwt[(size_t)(c0 + row) * 896 + ks * 128 + c8];
        }
        __syncthreads();
        int arow = (wave << 4) + l16;
#pragma unroll
        for (int sub = 0; sub < 4; ++sub) {
            int kk = sub * 32 + quad * 8;
            bfrag8 af = *(const bfrag8*)&As[arow * 136 + kk];
#pragma unroll
            for (int nt = 0; nt < 4; ++nt) {
                bfrag8 bf = *(const bfrag8*)&Bs[(nt * 16 + l16) * 136 + kk];
                acc[nt] = __builtin_amdgcn_mfma_f32_16x16x32_bf16(af, bf, acc[nt], 0, 0, 0);
            }
        }
        __syncthreads();
    }
    int rbase = r0 + (wave << 4) + quad * 4;
#pragma unroll
    for (int nt = 0; nt < 4; ++nt) {
        int col = c0 + nt * 16 + l16;
        float bb = fb[col];
#pragma unroll
        for (int r = 0; r < 4; ++r)
            z[(size_t)(rbase + r) * 448 + col] = fmaxf(acc[nt][r] + bb, 0.f);
    }
}

// ---------------- MLP fc2 + sigmoid: wave per row, 4 rows/block ----------------
__global__ __launch_bounds__(256) void k_mlp2(const float* __restrict__ z,
                                              const float* __restrict__ w,
                                              const float* __restrict__ b,
                                              float* __restrict__ out) {
    int r = blockIdx.x * 4 + (threadIdx.x >> 6);
    int lane = threadIdx.x & 63;
    float acc = 0.f;
#pragma unroll
    for (int i = 0; i < 7; ++i) {
        int c = lane + i * 64;
        acc += z[(size_t)r * 448 + c] * w[c];
    }
#pragma unroll
    for (int off = 32; off > 0; off >>= 1) acc += __shfl_down(acc, off, 64);
    if (lane == 0) {
        float lg = acc + b[0];
        out[r] = 1.f / (1.f + expf(-lg));
    }
}

extern "C" void kernel_launch(void* const* d_in, const int* in_sizes, int n_in,
                              void* d_out, int out_size, void* d_ws, size_t ws_size,
                              hipStream_t stream) {
    const float* bert = (const float*)d_in[0];
    const float* x    = (const float*)d_in[1];
    const int*   ei   = (const int*)d_in[2];
    const int*   ent  = (const int*)d_in[3];
    const float* W1   = (const float*)d_in[4];
    const float* b1   = (const float*)d_in[5];
    const float* W2   = (const float*)d_in[6];
    const float* b2   = (const float*)d_in[7];
    const float* fc1w = (const float*)d_in[8];
    const float* fc1b = (const float*)d_in[9];
    const float* fc2w = (const float*)d_in[10];
    const float* fc2b = (const float*)d_in[11];
    float* out = (float*)d_out;

    const int N = in_sizes[1] / 128;   // 50000 (< 65536 required for 16-bit packing)
    const int E = in_sizes[2] / 2;     // 800000
    const int B = in_sizes[0] / 768;   // 4096

    const int* srcv = ei;
    const int* dstv = ei + E;

    char* wsp = (char*)d_ws;
    size_t off = 0;
    auto alloc = [&](size_t bytes) -> void* {
        void* p = wsp + off;
        off += (bytes + 255) & ~(size_t)255;
        return p;
    };
    float* dinv   = (float*)alloc((size_t)N * 4);
    int*   offs   = (int*)alloc((size_t)(N + 1) * 4);
    int*   bcnt   = (int*)alloc(NBUCK * 4);
    int*   bstart = (int*)alloc(NBUCK * 4);
    unsigned int*   ebuf  = (unsigned int*)alloc((size_t)NBUCK * BCAP * 4);   // 8 MB
    unsigned short* csr16 = (unsigned short*)alloc((size_t)E * 2);
    bf16_t* bertb = (bf16_t*)alloc((size_t)B * 768 * 2);
    bf16_t* w1t   = (bf16_t*)alloc(128 * 128 * 2);
    bf16_t* w2t   = (bf16_t*)alloc(128 * 128 * 2);
    bf16_t* fwt   = (bf16_t*)alloc((size_t)896 * 448 * 2);
    bf16_t* gbuf  = (bf16_t*)alloc((size_t)N * 128 * 2);   // h' = (hW)*dinv
    bf16_t* hbuf  = (bf16_t*)alloc((size_t)N * 128 * 2);   // agg out (post-relu)
    bf16_t* gnnb  = (bf16_t*)alloc((size_t)B * 128 * 2);
    float* zbuf   = (float*)alloc((size_t)B * 448 * 4);
    (void)ws_size; (void)n_in; (void)out_size;

    hipMemsetAsync(bcnt, 0, NBUCK * 4, stream);

    k_bin2  <<<(E + 4095) / 4096, 256, 0, stream>>>(srcv, dstv, bcnt, ebuf, E, N);
    k_bscan <<<1, 256, 0, stream>>>(bcnt, bstart, offs, N, E);
    k_build2<<<NBUCK, 256, 0, stream>>>(ebuf, bcnt, bstart, offs, dinv, csr16, N);

    int nb8 = B * 768 / 8;
    k_cvt<<<(nb8 + 255) / 256, 256, 0, stream>>>(bert, (unsigned int*)bertb, nb8);
    k_prepw_s<<<(32768 + 255) / 256, 256, 0, stream>>>(W1, (unsigned short*)w1t,
                                                       W2, (unsigned short*)w2t);
    k_tpose<<<dim3(448 / 64, 896 / 64), 256, 0, stream>>>(fc1w, (unsigned short*)fwt);

    int gb = (N + 63) / 64;
    k_gemm_f32a<<<gb, 256, 0, stream>>>(x, w1t, dinv, gbuf, N);
    k_agg_b<<<(N + 3) / 4, 256, 0, stream>>>((const unsigned int*)gbuf, csr16, offs, dinv, b1,
                                             (unsigned int*)hbuf, N);
    k_gemm_nn128<<<gb, 256, 0, stream>>>(hbuf, w2t, dinv, gbuf, N);
    k_agg_b<<<(N + 3) / 4, 256, 0, stream>>>((const unsigned int*)gbuf, csr16, offs, dinv, b2,
                                             (unsigned int*)hbuf, N);
    k_pool_b<<<B / 4, 256, 0, stream>>>((const unsigned int*)hbuf, ent, (unsigned int*)gnnb);
    k_mlp1_mfma<<<dim3(B / 64, 7), 256, 0, stream>>>(bertb, gnnb, fwt, fc1b, zbuf);
    k_mlp2<<<B / 4, 256, 0, stream>>>(zbuf, fc2w, fc2b, out);
}

// Round 8
// 221.972 us; speedup vs baseline: 1.4013x; 1.0709x over previous
//
#include <hip/hip_runtime.h>
#include <math.h>

typedef __bf16 bf16_t;
typedef __bf16 bfrag8 __attribute__((ext_vector_type(8)));
typedef float  facc4  __attribute__((ext_vector_type(4)));
typedef float  f32x2  __attribute__((ext_vector_type(2)));

#define NBUCK 512   // dst-buckets for CSR multisplit (requires N < 65536 for 16-bit packing)
#define BCAP  4096  // per-bucket ebuf capacity (mean 1568, sd ~40)

__device__ inline unsigned short f2b(float x) {          // RNE float->bf16 bits
    unsigned int u = __float_as_uint(x);
    unsigned int r = (u + 0x7fffu + ((u >> 16) & 1u)) >> 16;
    return (unsigned short)r;
}
__device__ inline unsigned int pack2(float lo, float hi) {
    return (unsigned int)f2b(lo) | ((unsigned int)f2b(hi) << 16);
}
__device__ inline float blo(unsigned int q) { return __uint_as_float(q << 16); }
__device__ inline float bhi(unsigned int q) { return __uint_as_float(q & 0xffff0000u); }

// ---- fp8 e4m3 (OCP) encode/decode: HW cvt path with portable fallback ----
#if __has_builtin(__builtin_amdgcn_cvt_pk_f32_fp8) && __has_builtin(__builtin_amdgcn_cvt_pk_fp8_f32)
#define HW_FP8 1
#endif

__device__ inline f32x2 fp8pair_dec(unsigned short v) {
#ifdef HW_FP8
    return __builtin_amdgcn_cvt_pk_f32_fp8((int)(unsigned int)v, false);
#else
    f32x2 r;
    unsigned char b0 = (unsigned char)(v & 0xff), b1 = (unsigned char)(v >> 8);
    {
        int e = (b0 >> 3) & 0xf, m = b0 & 7;
        float mag = e ? ldexpf(8.f + m, e - 10) : ldexpf((float)m, -9);
        r.x = (b0 & 0x80) ? -mag : mag;
    }
    {
        int e = (b1 >> 3) & 0xf, m = b1 & 7;
        float mag = e ? ldexpf(8.f + m, e - 10) : ldexpf((float)m, -9);
        r.y = (b1 & 0x80) ? -mag : mag;
    }
    return r;
#endif
}
__device__ inline unsigned char fp8_enc(float x) {
#ifdef HW_FP8
    return (unsigned char)(__builtin_amdgcn_cvt_pk_fp8_f32(x, x, 0, false) & 0xff);
#else
    unsigned char s = (x < 0.f) ? 0x80 : 0;
    float ax = fabsf(x);
    if (!(ax > 0.f)) return s;
    if (ax >= 448.f) return s | 0x7e;
    if (ax < 0.015625f) {
        int q = (int)rintf(ax * 512.f);
        return s | (unsigned char)q;
    }
    int e; float m = frexpf(ax, &e);
    int q = (int)rintf(m * 16.f);
    int E = e - 1;
    if (q == 16) { q = 8; ++E; }
    if (E > 8) return s | 0x7e;
    return s | (unsigned char)(((E + 7) << 3) | (q - 8));
#endif
}

__device__ inline int bucket_of(int d, int N) {
    return (int)(((long long)d * NBUCK) / N);
}

// ---------------- CSR build, pass 1: LDS multisplit into per-bucket ebuf regions.
__global__ __launch_bounds__(256) void k_bin2(const int* __restrict__ src,
                                              const int* __restrict__ dst,
                                              int* __restrict__ bcnt,
                                              unsigned int* __restrict__ ebuf,
                                              int E, int N) {
    __shared__ unsigned int sorted[4096];
    __shared__ int hist[NBUCK];
    __shared__ int lstart[NBUCK];
    __shared__ int gbase[NBUCK];
    __shared__ int sm[256];
    int tid = threadIdx.x;
    int base = blockIdx.x * 4096;
    int cnt = min(4096, E - base);
    hist[tid] = 0; hist[tid + 256] = 0;
    __syncthreads();
    unsigned int mye[16]; int myb[16];
#pragma unroll
    for (int i = 0; i < 16; ++i) {
        int idx = i * 256 + tid;
        myb[i] = -1;
        if (idx < cnt) {
            int e = base + idx;
            int s = src[e], d = dst[e];
            mye[i] = ((unsigned int)s << 16) | (unsigned int)d;   // needs s,d < 65536
            int b = bucket_of(d, N);
            myb[i] = b;
            atomicAdd(&hist[b], 1);
        }
    }
    __syncthreads();
    int p0 = hist[2 * tid], p1 = hist[2 * tid + 1];
    sm[tid] = p0 + p1;
    __syncthreads();
    for (int off = 1; off < 256; off <<= 1) {
        int x = (tid >= off) ? sm[tid - off] : 0;
        __syncthreads();
        sm[tid] += x;
        __syncthreads();
    }
    int excl = sm[tid] - (p0 + p1);
    lstart[2 * tid] = excl;
    lstart[2 * tid + 1] = excl + p0;
    __syncthreads();
    hist[tid] = lstart[tid]; hist[tid + 256] = lstart[tid + 256];
    __syncthreads();
#pragma unroll
    for (int i = 0; i < 16; ++i) {
        if (myb[i] >= 0) {
            int pos = atomicAdd(&hist[myb[i]], 1);
            sorted[pos] = mye[i];
        }
    }
    __syncthreads();
    for (int b = tid; b < NBUCK; b += 256) {
        int c = hist[b] - lstart[b];
        gbase[b] = (c > 0) ? atomicAdd(&bcnt[b], c) : 0;
    }
    __syncthreads();
    for (int idx = tid; idx < cnt; idx += 256) {
        unsigned int v = sorted[idx];
        int b = bucket_of((int)(v & 0xffffu), N);
        ebuf[(size_t)b * BCAP + gbase[b] + (idx - lstart[b])] = v;
    }
}

// ---------------- pass 2: scan 512 bucket totals -> global CSR bucket starts ----
__global__ void k_bscan(const int* __restrict__ bcnt, int* __restrict__ bstart,
                        int* __restrict__ offs, int N, int E) {
    __shared__ int sm[256];
    int t = threadIdx.x;
    int v0 = bcnt[2 * t], v1 = bcnt[2 * t + 1];
    sm[t] = v0 + v1;
    __syncthreads();
    for (int off = 1; off < 256; off <<= 1) {
        int x = (t >= off) ? sm[t - off] : 0;
        __syncthreads();
        sm[t] += x;
        __syncthreads();
    }
    int excl = sm[t] - (v0 + v1);
    bstart[2 * t] = excl;
    bstart[2 * t + 1] = excl + v0;
    if (t == 0) offs[N] = E;
}

// ---------------- pass 3: per-bucket node counts/offsets/dinv in LDS, coalesced CSR out.
__global__ __launch_bounds__(256) void k_build2(const unsigned int* __restrict__ ebuf,
                                                const int* __restrict__ bcnt,
                                                const int* __restrict__ bstart,
                                                int* __restrict__ offs,
                                                float* __restrict__ dinv,
                                                unsigned short* __restrict__ csr, int N) {
    __shared__ unsigned short seg[BCAP];
    __shared__ int cnt_l[128];
    __shared__ int scan_l[128];
    __shared__ int curs[128];
    int b = blockIdx.x, tid = threadIdx.x;
    int lo = (int)(((long long)b * N + NBUCK - 1) / NBUCK);
    int cnt = bcnt[b];
    int base = bstart[b];
    int nrange = (int)(((long long)(b + 1) * N + NBUCK - 1) / NBUCK) - lo;   // <= 98
    if (tid < 128) cnt_l[tid] = 0;
    __syncthreads();
    for (int i = tid; i < cnt; i += 256) {
        unsigned int v = ebuf[(size_t)b * BCAP + i];
        atomicAdd(&cnt_l[(int)(v & 0xffffu) - lo], 1);
    }
    __syncthreads();
    if (tid < 128) scan_l[tid] = cnt_l[tid];
    __syncthreads();
    for (int off = 1; off < 128; off <<= 1) {
        int x = 0;
        if (tid < 128 && tid >= off) x = scan_l[tid - off];
        __syncthreads();
        if (tid < 128) scan_l[tid] += x;
        __syncthreads();
    }
    if (tid < 128) {
        int excl = scan_l[tid] - cnt_l[tid];
        curs[tid] = excl;
        if (tid < nrange) {
            offs[lo + tid] = base + excl;
            dinv[lo + tid] = rsqrtf((float)(cnt_l[tid] + 1));   // +1 = self loop
        }
    }
    __syncthreads();
    for (int i = tid; i < cnt; i += 256) {
        unsigned int v = ebuf[(size_t)b * BCAP + i];
        int d = (int)(v & 0xffffu) - lo;
        int p = atomicAdd(&curs[d], 1);
        seg[p] = (unsigned short)(v >> 16);
    }
    __syncthreads();
    for (int i = tid; i < cnt; i += 256) csr[base + i] = seg[i];
}

// ---------------- fp32 -> bf16 conversion (bert only) ----------------
__global__ void k_cvt(const float* __restrict__ in, unsigned int* __restrict__ outb, int n8) {
    int i = blockIdx.x * 256 + threadIdx.x;
    if (i >= n8) return;
    const float4* p = (const float4*)in + (size_t)i * 2;
    float4 a = p[0], b = p[1];
    uint4 o;
    o.x = pack2(a.x, a.y);
    o.y = pack2(a.z, a.w);
    o.z = pack2(b.x, b.y);
    o.w = pack2(b.z, b.w);
    ((uint4*)outb)[i] = o;
}

// ---------------- small weight transpose+cvt for W1, W2 ----------------
__global__ void k_prepw_s(const float* __restrict__ W1, unsigned short* __restrict__ w1t,
                          const float* __restrict__ W2, unsigned short* __restrict__ w2t) {
    int i = blockIdx.x * 256 + threadIdx.x;
    if (i >= 32768) return;
    const float* W = (i < 16384) ? W1 : W2;
    unsigned short* Wt = (i < 16384) ? w1t : w2t;
    int idx = i & 16383;
    int n = idx >> 7, k = idx & 127;
    Wt[idx] = f2b(W[k * 128 + n]);
}

// ---------------- tiled transpose+cvt for fc1w ----------------
__global__ __launch_bounds__(256) void k_tpose(const float* __restrict__ Wf,
                                               unsigned short* __restrict__ fwt) {
    __shared__ float tile[64][65];
    int n0 = blockIdx.x * 64, k0 = blockIdx.y * 64;
#pragma unroll
    for (int i = 0; i < 16; ++i) {
        int idx = i * 256 + threadIdx.x;
        int r = idx >> 6, c = idx & 63;
        tile[r][c] = Wf[(size_t)(k0 + r) * 448 + n0 + c];
    }
    __syncthreads();
#pragma unroll
    for (int i = 0; i < 16; ++i) {
        int idx = i * 256 + threadIdx.x;
        int c = idx >> 6, r = idx & 63;
        fwt[(size_t)(n0 + c) * 896 + k0 + r] = f2b(tile[r][c]);
    }
}

// ---------------- MFMA GEMM (fp32 A, inline cvt): out8 = fp8((A @ Bt^T) * rs) ----
__global__ __launch_bounds__(256) void k_gemm_f32a(const float* __restrict__ A,
                                                   const bf16_t* __restrict__ Bt,
                                                   const float* __restrict__ rs,
                                                   unsigned char* __restrict__ out8, int M) {
    __shared__ bf16_t As[64 * 136];
    __shared__ bf16_t Bs[128 * 136];
    int t = threadIdx.x;
    int wave = t >> 6, lane = t & 63, quad = lane >> 4, l16 = lane & 15;
    int r0 = blockIdx.x * 64;
#pragma unroll
    for (int i = 0; i < 4; ++i) {
        int chunk = t + i * 256;
        int row = chunk >> 4, c8 = (chunk & 15) << 3;
        int gr = r0 + row;
        float4 a0 = make_float4(0.f, 0.f, 0.f, 0.f), a1 = a0;
        if (gr < M) {
            a0 = *(const float4*)&A[(size_t)gr * 128 + c8];
            a1 = *(const float4*)&A[(size_t)gr * 128 + c8 + 4];
        }
        *(uint4*)&As[row * 136 + c8] =
            make_uint4(pack2(a0.x, a0.y), pack2(a0.z, a0.w),
                       pack2(a1.x, a1.y), pack2(a1.z, a1.w));
    }
#pragma unroll
    for (int i = 0; i < 8; ++i) {
        int chunk = t + i * 256;
        int row = chunk >> 4, c8 = (chunk & 15) << 3;
        *(uint4*)&Bs[row * 136 + c8] = *(const uint4*)&Bt[row * 128 + c8];
    }
    __syncthreads();

    facc4 acc[8];
#pragma unroll
    for (int nt = 0; nt < 8; ++nt) acc[nt] = (facc4){0.f, 0.f, 0.f, 0.f};
    int arow = (wave << 4) + l16;
#pragma unroll
    for (int ks = 0; ks < 4; ++ks) {
        int kk = ks * 32 + quad * 8;
        bfrag8 af = *(const bfrag8*)&As[arow * 136 + kk];
#pragma unroll
        for (int nt = 0; nt < 8; ++nt) {
            bfrag8 bf = *(const bfrag8*)&Bs[(nt * 16 + l16) * 136 + kk];
            acc[nt] = __builtin_amdgcn_mfma_f32_16x16x32_bf16(af, bf, acc[nt], 0, 0, 0);
        }
    }
    // epilogue: fp8-encode into LDS tile (reuse As), then coalesced byte-out
    __syncthreads();
    unsigned char* f8t = (unsigned char*)As;   // 64*128 bytes
    int wrow0 = (wave << 4) + quad * 4;
#pragma unroll
    for (int r = 0; r < 4; ++r) {
        int row = wrow0 + r;
        float sc = rs[min(r0 + row, M - 1)];
#pragma unroll
        for (int nt = 0; nt < 8; ++nt)
            f8t[row * 128 + nt * 16 + l16] = fp8_enc(acc[nt][r] * sc);
    }
    __syncthreads();
#pragma unroll
    for (int i = 0; i < 2; ++i) {
        int idx = t + i * 256;              // 512 chunks of 16B
        int row = idx >> 3, cc = (idx & 7) << 4;
        int gr = r0 + row;
        if (gr < M) *(uint4*)&out8[(size_t)gr * 128 + cc] = *(const uint4*)&f8t[row * 128 + cc];
    }
}

// ---------------- MFMA GEMM (bf16 A): out8 = fp8((A @ Bt^T) * rs) ----------------
__global__ __launch_bounds__(256) void k_gemm_nn128(const bf16_t* __restrict__ A,
                                                    const bf16_t* __restrict__ Bt,
                                                    const float* __restrict__ rs,
                                                    unsigned char* __restrict__ out8, int M) {
    __shared__ bf16_t As[64 * 136];
    __shared__ bf16_t Bs[128 * 136];
    int t = threadIdx.x;
    int wave = t >> 6, lane = t & 63, quad = lane >> 4, l16 = lane & 15;
    int r0 = blockIdx.x * 64;
#pragma unroll
    for (int i = 0; i < 4; ++i) {
        int chunk = t + i * 256;
        int row = chunk >> 4, c8 = (chunk & 15) << 3;
        int gr = r0 + row;
        uint4 v = make_uint4(0u, 0u, 0u, 0u);
        if (gr < M) v = *(const uint4*)&A[(size_t)gr * 128 + c8];
        *(uint4*)&As[row * 136 + c8] = v;
    }
#pragma unroll
    for (int i = 0; i < 8; ++i) {
        int chunk = t + i * 256;
        int row = chunk >> 4, c8 = (chunk & 15) << 3;
        *(uint4*)&Bs[row * 136 + c8] = *(const uint4*)&Bt[row * 128 + c8];
    }
    __syncthreads();

    facc4 acc[8];
#pragma unroll
    for (int nt = 0; nt < 8; ++nt) acc[nt] = (facc4){0.f, 0.f, 0.f, 0.f};
    int arow = (wave << 4) + l16;
#pragma unroll
    for (int ks = 0; ks < 4; ++ks) {
        int kk = ks * 32 + quad * 8;
        bfrag8 af = *(const bfrag8*)&As[arow * 136 + kk];
#pragma unroll
        for (int nt = 0; nt < 8; ++nt) {
            bfrag8 bf = *(const bfrag8*)&Bs[(nt * 16 + l16) * 136 + kk];
            acc[nt] = __builtin_amdgcn_mfma_f32_16x16x32_bf16(af, bf, acc[nt], 0, 0, 0);
        }
    }
    __syncthreads();
    unsigned char* f8t = (unsigned char*)As;
    int wrow0 = (wave << 4) + quad * 4;
#pragma unroll
    for (int r = 0; r < 4; ++r) {
        int row = wrow0 + r;
        float sc = rs[min(r0 + row, M - 1)];
#pragma unroll
        for (int nt = 0; nt < 8; ++nt)
            f8t[row * 128 + nt * 16 + l16] = fp8_enc(acc[nt][r] * sc);
    }
    __syncthreads();
#pragma unroll
    for (int i = 0; i < 2; ++i) {
        int idx = t + i * 256;
        int row = idx >> 3, cc = (idx & 7) << 4;
        int gr = r0 + row;
        if (gr < M) *(uint4*)&out8[(size_t)gr * 128 + cc] = *(const uint4*)&f8t[row * 128 + cc];
    }
}

// ---------------- aggregation: wave per node, fp8 gather (128 B/row) ----------------
// hx8 = fp8(h') where h' = (hW)*dinv;  out[n] = relu(dinv[n]*(sum_src h'[src] + h'[n]) + bias)
__global__ __launch_bounds__(256) void k_agg_b(const unsigned short* __restrict__ hx8, // [N][64]
                                               const unsigned short* __restrict__ csr,
                                               const int* __restrict__ offs,
                                               const float* __restrict__ dinv,
                                               const float* __restrict__ bias,
                                               unsigned int* __restrict__ out, int N) {
    int node = blockIdx.x * 4 + (threadIdx.x >> 6);
    int lane = threadIdx.x & 63;
    if (node >= N) return;
    float di = dinv[node];
    f32x2 sf = fp8pair_dec(hx8[(size_t)node * 64 + lane]);
    float acc0 = sf.x, acc1 = sf.y;                   // self term (already *dinv)
    int s0 = offs[node], s1 = offs[node + 1];
    for (int base = s0; base < s1; base += 64) {
        int nloc = min(64, s1 - base);
        int en = 0;
        if (lane < nloc) en = (int)csr[base + lane];
        int j = 0;
        for (; j + 16 <= nloc; j += 16) {
            int sid[16]; unsigned short g[16];
#pragma unroll
            for (int u = 0; u < 16; ++u) sid[u] = __shfl(en, j + u, 64);
#pragma unroll
            for (int u = 0; u < 16; ++u) g[u] = hx8[(size_t)sid[u] * 64 + lane];  // 16 in flight
#pragma unroll
            for (int u = 0; u < 16; ++u) { f32x2 d = fp8pair_dec(g[u]); acc0 += d.x; acc1 += d.y; }
        }
        for (; j + 4 <= nloc; j += 4) {
            int sid[4]; unsigned short g[4];
#pragma unroll
            for (int u = 0; u < 4; ++u) sid[u] = __shfl(en, j + u, 64);
#pragma unroll
            for (int u = 0; u < 4; ++u) g[u] = hx8[(size_t)sid[u] * 64 + lane];
#pragma unroll
            for (int u = 0; u < 4; ++u) { f32x2 d = fp8pair_dec(g[u]); acc0 += d.x; acc1 += d.y; }
        }
        for (; j < nloc; ++j) {
            int srcn = __shfl(en, j, 64);
            f32x2 d = fp8pair_dec(hx8[(size_t)srcn * 64 + lane]);
            acc0 += d.x; acc1 += d.y;
        }
    }
    float2 bb = *(const float2*)&bias[lane * 2];
    float v0 = fmaxf(acc0 * di + bb.x, 0.f);
    float v1 = fmaxf(acc1 * di + bb.y, 0.f);
    out[(size_t)node * 64 + lane] = pack2(v0, v1);
}

// ---------------- entity mean pool (bf16 in/out): wave per row ----------------
__global__ __launch_bounds__(256) void k_pool_b(const unsigned int* __restrict__ h,
                                                const int* __restrict__ ent,
                                                unsigned int* __restrict__ out) {
    int r = blockIdx.x * 4 + (threadIdx.x >> 6);
    int lane = threadIdx.x & 63;
    float a0 = 0.f, a1 = 0.f;
    int cnt = 0;
#pragma unroll
    for (int m = 0; m < 20; ++m) {
        int id = ent[r * 20 + m];
        if (id >= 0) {
            unsigned int q = h[(size_t)id * 64 + lane];
            a0 += blo(q); a1 += bhi(q); cnt++;
        }
    }
    float inv = 1.f / (float)max(cnt, 1);
    out[(size_t)r * 64 + lane] = pack2(a0 * inv, a1 * inv);
}

// ---------------- MLP fc1 (MFMA): z = relu([bertb|gnnb] @ fc1wt + fc1_b), z fp32
__global__ __launch_bounds__(256) void k_mlp1_mfma(const bf16_t* __restrict__ bertb,
                                                   const bf16_t* __restrict__ gnnb,
                                                   const bf16_t* __restrict__ fwt,  // [448][896]
                                                   const float* __restrict__ fb,
                                                   float* __restrict__ z) {
    __shared__ bf16_t As[64 * 136];
    __shared__ bf16_t Bs[64 * 136];
    int t = threadIdx.x;
    int wave = t >> 6, lane = t & 63, quad = lane >> 4, l16 = lane & 15;
    int r0 = blockIdx.x * 64, c0 = blockIdx.y * 64;
    facc4 acc[4];
#pragma unroll
    for (int nt = 0; nt < 4; ++nt) acc[nt] = (facc4){0.f, 0.f, 0.f, 0.f};

    for (int ks = 0; ks < 7; ++ks) {
#pragma unroll
        for (int i = 0; i < 4; ++i) {
            int chunk = t + i * 256;
            int row = chunk >> 4, c8 = (chunk & 15) << 3;
            int gr = r0 + row;
            const bf16_t* srcp = (ks < 6) ? &bertb[(size_t)gr * 768 + ks * 128 + c8]
                                          : &gnnb[(size_t)gr * 128 + c8];
            *(uint4*)&As[row * 136 + c8] = *(const uint4*)srcp;
        }
#pragma unroll
        for (int i = 0; i < 4; ++i) {
            int chunk = t + i * 256;
            int row = chunk >> 4, c8 = (chunk & 15) << 3;
            *(uint4*)&Bs[row * 136 + c8] =
                *(const uint4*)&fwt[(size_t)(c0 + row) * 896 + ks * 128 + c8];
        }
        __syncthreads();
        int arow = (wave << 4) + l16;
#pragma unroll
        for (int sub = 0; sub < 4; ++sub) {
            int kk = sub * 32 + quad * 8;
            bfrag8 af = *(const bfrag8*)&As[arow * 136 + kk];
#pragma unroll
            for (int nt = 0; nt < 4; ++nt) {
                bfrag8 bf = *(const bfrag8*)&Bs[(nt * 16 + l16) * 136 + kk];
                acc[nt] = __builtin_amdgcn_mfma_f32_16x16x32_bf16(af, bf, acc[nt], 0, 0, 0);
            }
        }
        __syncthreads();
    }
    int rbase = r0 + (wave << 4) + quad * 4;
#pragma unroll
    for (int nt = 0; nt < 4; ++nt) {
        int col = c0 + nt * 16 + l16;
        float bb = fb[col];
#pragma unroll
        for (int r = 0; r < 4; ++r)
            z[(size_t)(rbase + r) * 448 + col] = fmaxf(acc[nt][r] + bb, 0.f);
    }
}

// ---------------- MLP fc2 + sigmoid: wave per row, 4 rows/block ----------------
__global__ __launch_bounds__(256) void k_mlp2(const float* __restrict__ z,
                                              const float* __restrict__ w,
                                              const float* __restrict__ b,
                                              float* __restrict__ out) {
    int r = blockIdx.x * 4 + (threadIdx.x >> 6);
    int lane = threadIdx.x & 63;
    float acc = 0.f;
#pragma unroll
    for (int i = 0; i < 7; ++i) {
        int c = lane + i * 64;
        acc += z[(size_t)r * 448 + c] * w[c];
    }
#pragma unroll
    for (int off = 32; off > 0; off >>= 1) acc += __shfl_down(acc, off, 64);
    if (lane == 0) {
        float lg = acc + b[0];
        out[r] = 1.f / (1.f + expf(-lg));
    }
}

extern "C" void kernel_launch(void* const* d_in, const int* in_sizes, int n_in,
                              void* d_out, int out_size, void* d_ws, size_t ws_size,
                              hipStream_t stream) {
    const float* bert = (const float*)d_in[0];
    const float* x    = (const float*)d_in[1];
    const int*   ei   = (const int*)d_in[2];
    const int*   ent  = (const int*)d_in[3];
    const float* W1   = (const float*)d_in[4];
    const float* b1   = (const float*)d_in[5];
    const float* W2   = (const float*)d_in[6];
    const float* b2   = (const float*)d_in[7];
    const float* fc1w = (const float*)d_in[8];
    const float* fc1b = (const float*)d_in[9];
    const float* fc2w = (const float*)d_in[10];
    const float* fc2b = (const float*)d_in[11];
    float* out = (float*)d_out;

    const int N = in_sizes[1] / 128;   // 50000 (< 65536 required for 16-bit packing)
    const int E = in_sizes[2] / 2;     // 800000
    const int B = in_sizes[0] / 768;   // 4096

    const int* srcv = ei;
    const int* dstv = ei + E;

    char* wsp = (char*)d_ws;
    size_t off = 0;
    auto alloc = [&](size_t bytes) -> void* {
        void* p = wsp + off;
        off += (bytes + 255) & ~(size_t)255;
        return p;
    };
    float* dinv   = (float*)alloc((size_t)N * 4);
    int*   offs   = (int*)alloc((size_t)(N + 1) * 4);
    int*   bcnt   = (int*)alloc(NBUCK * 4);
    int*   bstart = (int*)alloc(NBUCK * 4);
    unsigned int*   ebuf  = (unsigned int*)alloc((size_t)NBUCK * BCAP * 4);   // 8 MB
    unsigned short* csr16 = (unsigned short*)alloc((size_t)E * 2);
    bf16_t* bertb = (bf16_t*)alloc((size_t)B * 768 * 2);
    bf16_t* w1t   = (bf16_t*)alloc(128 * 128 * 2);
    bf16_t* w2t   = (bf16_t*)alloc(128 * 128 * 2);
    bf16_t* fwt   = (bf16_t*)alloc((size_t)896 * 448 * 2);
    unsigned char* g8buf = (unsigned char*)alloc((size_t)N * 128);   // fp8 h' = (hW)*dinv
    bf16_t* hbuf  = (bf16_t*)alloc((size_t)N * 128 * 2);             // agg out (post-relu)
    bf16_t* gnnb  = (bf16_t*)alloc((size_t)B * 128 * 2);
    float* zbuf   = (float*)alloc((size_t)B * 448 * 4);
    (void)ws_size; (void)n_in; (void)out_size;

    hipMemsetAsync(bcnt, 0, NBUCK * 4, stream);

    k_bin2  <<<(E + 4095) / 4096, 256, 0, stream>>>(srcv, dstv, bcnt, ebuf, E, N);
    k_bscan <<<1, 256, 0, stream>>>(bcnt, bstart, offs, N, E);
    k_build2<<<NBUCK, 256, 0, stream>>>(ebuf, bcnt, bstart, offs, dinv, csr16, N);

    int nb8 = B * 768 / 8;
    k_cvt<<<(nb8 + 255) / 256, 256, 0, stream>>>(bert, (unsigned int*)bertb, nb8);
    k_prepw_s<<<(32768 + 255) / 256, 256, 0, stream>>>(W1, (unsigned short*)w1t,
                                                       W2, (unsigned short*)w2t);
    k_tpose<<<dim3(448 / 64, 896 / 64), 256, 0, stream>>>(fc1w, (unsigned short*)fwt);

    int gb = (N + 63) / 64;
    k_gemm_f32a<<<gb, 256, 0, stream>>>(x, w1t, dinv, g8buf, N);
    k_agg_b<<<(N + 3) / 4, 256, 0, stream>>>((const unsigned short*)g8buf, csr16, offs, dinv, b1,
                                             (unsigned int*)hbuf, N);
    k_gemm_nn128<<<gb, 256, 0, stream>>>(hbuf, w2t, dinv, g8buf, N);
    k_agg_b<<<(N + 3) / 4, 256, 0, stream>>>((const unsigned short*)g8buf, csr16, offs, dinv, b2,
                                             (unsigned int*)hbuf, N);
    k_pool_b<<<B / 4, 256, 0, stream>>>((const unsigned int*)hbuf, ent, (unsigned int*)gnnb);
    k_mlp1_mfma<<<dim3(B / 64, 7), 256, 0, stream>>>(bertb, gnnb, fwt, fc1b, zbuf);
    k_mlp2<<<B / 4, 256, 0, stream>>>(zbuf, fc2w, fc2b, out);
}

// Round 9
// 217.613 us; speedup vs baseline: 1.4294x; 1.0200x over previous
//
#include <hip/hip_runtime.h>
#include <math.h>

typedef __bf16 bf16_t;
typedef __bf16 bfrag8 __attribute__((ext_vector_type(8)));
typedef float  facc4  __attribute__((ext_vector_type(4)));
typedef float  f32x2  __attribute__((ext_vector_type(2)));

#define NBUCK 512   // dst-buckets for CSR multisplit (requires N < 65536 for 16-bit packing)
#define BCAP  4096  // per-bucket ebuf capacity (mean 1568, sd ~40)

__device__ inline unsigned short f2b(float x) {          // RNE float->bf16 bits
    unsigned int u = __float_as_uint(x);
    unsigned int r = (u + 0x7fffu + ((u >> 16) & 1u)) >> 16;
    return (unsigned short)r;
}
__device__ inline unsigned int pack2(float lo, float hi) {
    return (unsigned int)f2b(lo) | ((unsigned int)f2b(hi) << 16);
}
__device__ inline float blo(unsigned int q) { return __uint_as_float(q << 16); }
__device__ inline float bhi(unsigned int q) { return __uint_as_float(q & 0xffff0000u); }

// ---- fp8 e4m3 (OCP) encode/decode: HW cvt path with portable fallback ----
#if __has_builtin(__builtin_amdgcn_cvt_pk_f32_fp8) && __has_builtin(__builtin_amdgcn_cvt_pk_fp8_f32)
#define HW_FP8 1
#endif

__device__ inline f32x2 fp8pair_dec(unsigned short v) {
#ifdef HW_FP8
    return __builtin_amdgcn_cvt_pk_f32_fp8((int)(unsigned int)v, false);
#else
    f32x2 r;
    unsigned char b0 = (unsigned char)(v & 0xff), b1 = (unsigned char)(v >> 8);
    {
        int e = (b0 >> 3) & 0xf, m = b0 & 7;
        float mag = e ? ldexpf(8.f + m, e - 10) : ldexpf((float)m, -9);
        r.x = (b0 & 0x80) ? -mag : mag;
    }
    {
        int e = (b1 >> 3) & 0xf, m = b1 & 7;
        float mag = e ? ldexpf(8.f + m, e - 10) : ldexpf((float)m, -9);
        r.y = (b1 & 0x80) ? -mag : mag;
    }
    return r;
#endif
}
__device__ inline unsigned char fp8_enc(float x) {
#ifdef HW_FP8
    return (unsigned char)(__builtin_amdgcn_cvt_pk_fp8_f32(x, x, 0, false) & 0xff);
#else
    unsigned char s = (x < 0.f) ? 0x80 : 0;
    float ax = fabsf(x);
    if (!(ax > 0.f)) return s;
    if (ax >= 448.f) return s | 0x7e;
    if (ax < 0.015625f) {
        int q = (int)rintf(ax * 512.f);
        return s | (unsigned char)q;
    }
    int e; float m = frexpf(ax, &e);
    int q = (int)rintf(m * 16.f);
    int E = e - 1;
    if (q == 16) { q = 8; ++E; }
    if (E > 8) return s | 0x7e;
    return s | (unsigned char)(((E + 7) << 3) | (q - 8));
#endif
}

__device__ inline int bucket_of(int d, int N) {
    return (int)(((long long)d * NBUCK) / N);
}

// ---------------- CSR build, pass 1: LDS multisplit into per-bucket ebuf regions.
__global__ __launch_bounds__(256) void k_bin2(const int* __restrict__ src,
                                              const int* __restrict__ dst,
                                              int* __restrict__ bcnt,
                                              unsigned int* __restrict__ ebuf,
                                              int E, int N) {
    __shared__ unsigned int sorted[4096];
    __shared__ int hist[NBUCK];
    __shared__ int lstart[NBUCK];
    __shared__ int gbase[NBUCK];
    __shared__ int sm[256];
    int tid = threadIdx.x;
    int base = blockIdx.x * 4096;
    int cnt = min(4096, E - base);
    hist[tid] = 0; hist[tid + 256] = 0;
    __syncthreads();
    unsigned int mye[16]; int myb[16];
#pragma unroll
    for (int i = 0; i < 16; ++i) {
        int idx = i * 256 + tid;
        myb[i] = -1;
        if (idx < cnt) {
            int e = base + idx;
            int s = src[e], d = dst[e];
            mye[i] = ((unsigned int)s << 16) | (unsigned int)d;   // needs s,d < 65536
            int b = bucket_of(d, N);
            myb[i] = b;
            atomicAdd(&hist[b], 1);
        }
    }
    __syncthreads();
    int p0 = hist[2 * tid], p1 = hist[2 * tid + 1];
    sm[tid] = p0 + p1;
    __syncthreads();
    for (int off = 1; off < 256; off <<= 1) {
        int x = (tid >= off) ? sm[tid - off] : 0;
        __syncthreads();
        sm[tid] += x;
        __syncthreads();
    }
    int excl = sm[tid] - (p0 + p1);
    lstart[2 * tid] = excl;
    lstart[2 * tid + 1] = excl + p0;
    __syncthreads();
    hist[tid] = lstart[tid]; hist[tid + 256] = lstart[tid + 256];
    __syncthreads();
#pragma unroll
    for (int i = 0; i < 16; ++i) {
        if (myb[i] >= 0) {
            int pos = atomicAdd(&hist[myb[i]], 1);
            sorted[pos] = mye[i];
        }
    }
    __syncthreads();
    for (int b = tid; b < NBUCK; b += 256) {
        int c = hist[b] - lstart[b];
        gbase[b] = (c > 0) ? atomicAdd(&bcnt[b], c) : 0;
    }
    __syncthreads();
    for (int idx = tid; idx < cnt; idx += 256) {
        unsigned int v = sorted[idx];
        int b = bucket_of((int)(v & 0xffffu), N);
        ebuf[(size_t)b * BCAP + gbase[b] + (idx - lstart[b])] = v;
    }
}

// ---------------- pass 2: per-bucket CSR build; bucket base via inline reduction.
__global__ __launch_bounds__(256) void k_build2(const unsigned int* __restrict__ ebuf,
                                                const int* __restrict__ bcnt,
                                                int* __restrict__ offs,
                                                float* __restrict__ dinv,
                                                unsigned short* __restrict__ csr,
                                                int N, int E) {
    __shared__ unsigned short seg[BCAP];
    __shared__ int cnt_l[128];
    __shared__ int scan_l[128];
    __shared__ int curs[128];
    __shared__ int smr[256];
    int b = blockIdx.x, tid = threadIdx.x;
    // base = sum bcnt[0..b) (512 values max -> 2 strided loads + LDS reduce)
    int part = 0;
    for (int j = tid; j < b; j += 256) part += bcnt[j];
    smr[tid] = part;
    __syncthreads();
    for (int off = 128; off > 0; off >>= 1) {
        if (tid < off) smr[tid] += smr[tid + off];
        __syncthreads();
    }
    int base = smr[0];
    int lo = (int)(((long long)b * N + NBUCK - 1) / NBUCK);
    int cnt = bcnt[b];
    int nrange = (int)(((long long)(b + 1) * N + NBUCK - 1) / NBUCK) - lo;   // <= 98
    if (b == 0 && tid == 0) offs[N] = E;
    if (tid < 128) cnt_l[tid] = 0;
    __syncthreads();
    for (int i = tid; i < cnt; i += 256) {
        unsigned int v = ebuf[(size_t)b * BCAP + i];
        atomicAdd(&cnt_l[(int)(v & 0xffffu) - lo], 1);
    }
    __syncthreads();
    if (tid < 128) scan_l[tid] = cnt_l[tid];
    __syncthreads();
    for (int off = 1; off < 128; off <<= 1) {
        int x = 0;
        if (tid < 128 && tid >= off) x = scan_l[tid - off];
        __syncthreads();
        if (tid < 128) scan_l[tid] += x;
        __syncthreads();
    }
    if (tid < 128) {
        int excl = scan_l[tid] - cnt_l[tid];
        curs[tid] = excl;
        if (tid < nrange) {
            offs[lo + tid] = base + excl;
            dinv[lo + tid] = rsqrtf((float)(cnt_l[tid] + 1));   // +1 = self loop
        }
    }
    __syncthreads();
    for (int i = tid; i < cnt; i += 256) {
        unsigned int v = ebuf[(size_t)b * BCAP + i];
        int d = (int)(v & 0xffffu) - lo;
        int p = atomicAdd(&curs[d], 1);
        seg[p] = (unsigned short)(v >> 16);
    }
    __syncthreads();
    for (int i = tid; i < cnt; i += 256) csr[base + i] = seg[i];
}

// ---------------- fused prep: bert cvt + W1/W2 transpose + fc1w tiled transpose
//                  + bcnt/logacc zeroing (one graph node) ----------------
__global__ __launch_bounds__(256) void k_prep(const float* __restrict__ bert,
                                              unsigned int* __restrict__ bertb, int n8,
                                              const float* __restrict__ W1,
                                              unsigned short* __restrict__ w1t,
                                              const float* __restrict__ W2,
                                              unsigned short* __restrict__ w2t,
                                              const float* __restrict__ Wf,
                                              unsigned short* __restrict__ fwt,
                                              int* __restrict__ bcnt,
                                              float* __restrict__ logacc) {
    __shared__ float tile[64][65];
    int ncvt = (n8 + 255) / 256;                   // 1536 blocks
    int bb = blockIdx.x, tid = threadIdx.x;
    if (bb < ncvt) {                               // bert fp32 -> bf16
        int i = bb * 256 + tid;
        if (i >= n8) return;
        const float4* p = (const float4*)bert + (size_t)i * 2;
        float4 a = p[0], b = p[1];
        uint4 o;
        o.x = pack2(a.x, a.y);
        o.y = pack2(a.z, a.w);
        o.z = pack2(b.x, b.y);
        o.w = pack2(b.z, b.w);
        ((uint4*)bertb)[i] = o;
        return;
    }
    bb -= ncvt;
    if (bb < 128) {                                // W1/W2 transpose (64KB each)
        int i = bb * 256 + tid;
        const float* W = (i < 16384) ? W1 : W2;
        unsigned short* Wt = (i < 16384) ? w1t : w2t;
        int idx = i & 16383;
        int n = idx >> 7, k = idx & 127;
        Wt[idx] = f2b(W[k * 128 + n]);
        return;
    }
    bb -= 128;
    if (bb < 98) {                                 // fc1w tiled transpose, 7 x 14
        int n0 = (bb % 7) * 64, k0 = (bb / 7) * 64;
#pragma unroll
        for (int i = 0; i < 16; ++i) {
            int idx = i * 256 + tid;
            int r = idx >> 6, c = idx & 63;
            tile[r][c] = Wf[(size_t)(k0 + r) * 448 + n0 + c];
        }
        __syncthreads();
#pragma unroll
        for (int i = 0; i < 16; ++i) {
            int idx = i * 256 + tid;
            int c = idx >> 6, r = idx & 63;
            fwt[(size_t)(n0 + c) * 896 + k0 + r] = f2b(tile[r][c]);
        }
        return;
    }
    // last block: zero bcnt (512) + logacc (4096)
    if (tid < 256) { bcnt[tid] = 0; bcnt[tid + 256] = 0; }
#pragma unroll
    for (int i = 0; i < 16; ++i) logacc[i * 256 + tid] = 0.f;
}

// ---------------- MFMA GEMM (fp32 A, inline cvt): out8 = fp8((A @ Bt^T) * rs) ----
__global__ __launch_bounds__(256) void k_gemm_f32a(const float* __restrict__ A,
                                                   const bf16_t* __restrict__ Bt,
                                                   const float* __restrict__ rs,
                                                   unsigned char* __restrict__ out8, int M) {
    __shared__ bf16_t As[64 * 136];
    __shared__ bf16_t Bs[128 * 136];
    int t = threadIdx.x;
    int wave = t >> 6, lane = t & 63, quad = lane >> 4, l16 = lane & 15;
    int r0 = blockIdx.x * 64;
#pragma unroll
    for (int i = 0; i < 4; ++i) {
        int chunk = t + i * 256;
        int row = chunk >> 4, c8 = (chunk & 15) << 3;
        int gr = r0 + row;
        float4 a0 = make_float4(0.f, 0.f, 0.f, 0.f), a1 = a0;
        if (gr < M) {
            a0 = *(const float4*)&A[(size_t)gr * 128 + c8];
            a1 = *(const float4*)&A[(size_t)gr * 128 + c8 + 4];
        }
        *(uint4*)&As[row * 136 + c8] =
            make_uint4(pack2(a0.x, a0.y), pack2(a0.z, a0.w),
                       pack2(a1.x, a1.y), pack2(a1.z, a1.w));
    }
#pragma unroll
    for (int i = 0; i < 8; ++i) {
        int chunk = t + i * 256;
        int row = chunk >> 4, c8 = (chunk & 15) << 3;
        *(uint4*)&Bs[row * 136 + c8] = *(const uint4*)&Bt[row * 128 + c8];
    }
    __syncthreads();

    facc4 acc[8];
#pragma unroll
    for (int nt = 0; nt < 8; ++nt) acc[nt] = (facc4){0.f, 0.f, 0.f, 0.f};
    int arow = (wave << 4) + l16;
#pragma unroll
    for (int ks = 0; ks < 4; ++ks) {
        int kk = ks * 32 + quad * 8;
        bfrag8 af = *(const bfrag8*)&As[arow * 136 + kk];
#pragma unroll
        for (int nt = 0; nt < 8; ++nt) {
            bfrag8 bf = *(const bfrag8*)&Bs[(nt * 16 + l16) * 136 + kk];
            acc[nt] = __builtin_amdgcn_mfma_f32_16x16x32_bf16(af, bf, acc[nt], 0, 0, 0);
        }
    }
    __syncthreads();
    unsigned char* f8t = (unsigned char*)As;   // 64*128 bytes
    int wrow0 = (wave << 4) + quad * 4;
#pragma unroll
    for (int r = 0; r < 4; ++r) {
        int row = wrow0 + r;
        float sc = rs[min(r0 + row, M - 1)];
#pragma unroll
        for (int nt = 0; nt < 8; ++nt)
            f8t[row * 128 + nt * 16 + l16] = fp8_enc(acc[nt][r] * sc);
    }
    __syncthreads();
#pragma unroll
    for (int i = 0; i < 2; ++i) {
        int idx = t + i * 256;              // 512 chunks of 16B
        int row = idx >> 3, cc = (idx & 7) << 4;
        int gr = r0 + row;
        if (gr < M) *(uint4*)&out8[(size_t)gr * 128 + cc] = *(const uint4*)&f8t[row * 128 + cc];
    }
}

// ---------------- MFMA GEMM (bf16 A): out8 = fp8((A @ Bt^T) * rs) ----------------
__global__ __launch_bounds__(256) void k_gemm_nn128(const bf16_t* __restrict__ A,
                                                    const bf16_t* __restrict__ Bt,
                                                    const float* __restrict__ rs,
                                                    unsigned char* __restrict__ out8, int M) {
    __shared__ bf16_t As[64 * 136];
    __shared__ bf16_t Bs[128 * 136];
    int t = threadIdx.x;
    int wave = t >> 6, lane = t & 63, quad = lane >> 4, l16 = lane & 15;
    int r0 = blockIdx.x * 64;
#pragma unroll
    for (int i = 0; i < 4; ++i) {
        int chunk = t + i * 256;
        int row = chunk >> 4, c8 = (chunk & 15) << 3;
        int gr = r0 + row;
        uint4 v = make_uint4(0u, 0u, 0u, 0u);
        if (gr < M) v = *(const uint4*)&A[(size_t)gr * 128 + c8];
        *(uint4*)&As[row * 136 + c8] = v;
    }
#pragma unroll
    for (int i = 0; i < 8; ++i) {
        int chunk = t + i * 256;
        int row = chunk >> 4, c8 = (chunk & 15) << 3;
        *(uint4*)&Bs[row * 136 + c8] = *(const uint4*)&Bt[row * 128 + c8];
    }
    __syncthreads();

    facc4 acc[8];
#pragma unroll
    for (int nt = 0; nt < 8; ++nt) acc[nt] = (facc4){0.f, 0.f, 0.f, 0.f};
    int arow = (wave << 4) + l16;
#pragma unroll
    for (int ks = 0; ks < 4; ++ks) {
        int kk = ks * 32 + quad * 8;
        bfrag8 af = *(const bfrag8*)&As[arow * 136 + kk];
#pragma unroll
        for (int nt = 0; nt < 8; ++nt) {
            bfrag8 bf = *(const bfrag8*)&Bs[(nt * 16 + l16) * 136 + kk];
            acc[nt] = __builtin_amdgcn_mfma_f32_16x16x32_bf16(af, bf, acc[nt], 0, 0, 0);
        }
    }
    __syncthreads();
    unsigned char* f8t = (unsigned char*)As;
    int wrow0 = (wave << 4) + quad * 4;
#pragma unroll
    for (int r = 0; r < 4; ++r) {
        int row = wrow0 + r;
        float sc = rs[min(r0 + row, M - 1)];
#pragma unroll
        for (int nt = 0; nt < 8; ++nt)
            f8t[row * 128 + nt * 16 + l16] = fp8_enc(acc[nt][r] * sc);
    }
    __syncthreads();
#pragma unroll
    for (int i = 0; i < 2; ++i) {
        int idx = t + i * 256;
        int row = idx >> 3, cc = (idx & 7) << 4;
        int gr = r0 + row;
        if (gr < M) *(uint4*)&out8[(size_t)gr * 128 + cc] = *(const uint4*)&f8t[row * 128 + cc];
    }
}

// ---------------- aggregation: wave per node, fp8 gather (128 B/row) ----------------
__global__ __launch_bounds__(256) void k_agg_b(const unsigned short* __restrict__ hx8, // [N][64]
                                               const unsigned short* __restrict__ csr,
                                               const int* __restrict__ offs,
                                               const float* __restrict__ dinv,
                                               const float* __restrict__ bias,
                                               unsigned int* __restrict__ out, int N) {
    int node = blockIdx.x * 4 + (threadIdx.x >> 6);
    int lane = threadIdx.x & 63;
    if (node >= N) return;
    float di = dinv[node];
    f32x2 sf = fp8pair_dec(hx8[(size_t)node * 64 + lane]);
    float acc0 = sf.x, acc1 = sf.y;                   // self term (already *dinv)
    int s0 = offs[node], s1 = offs[node + 1];
    for (int base = s0; base < s1; base += 64) {
        int nloc = min(64, s1 - base);
        int en = 0;
        if (lane < nloc) en = (int)csr[base + lane];
        int j = 0;
        for (; j + 16 <= nloc; j += 16) {
            int sid[16]; unsigned short g[16];
#pragma unroll
            for (int u = 0; u < 16; ++u) sid[u] = __shfl(en, j + u, 64);
#pragma unroll
            for (int u = 0; u < 16; ++u) g[u] = hx8[(size_t)sid[u] * 64 + lane];  // 16 in flight
#pragma unroll
            for (int u = 0; u < 16; ++u) { f32x2 d = fp8pair_dec(g[u]); acc0 += d.x; acc1 += d.y; }
        }
        for (; j + 4 <= nloc; j += 4) {
            int sid[4]; unsigned short g[4];
#pragma unroll
            for (int u = 0; u < 4; ++u) sid[u] = __shfl(en, j + u, 64);
#pragma unroll
            for (int u = 0; u < 4; ++u) g[u] = hx8[(size_t)sid[u] * 64 + lane];
#pragma unroll
            for (int u = 0; u < 4; ++u) { f32x2 d = fp8pair_dec(g[u]); acc0 += d.x; acc1 += d.y; }
        }
        for (; j < nloc; ++j) {
            int srcn = __shfl(en, j, 64);
            f32x2 d = fp8pair_dec(hx8[(size_t)srcn * 64 + lane]);
            acc0 += d.x; acc1 += d.y;
        }
    }
    float2 bb = *(const float2*)&bias[lane * 2];
    float v0 = fmaxf(acc0 * di + bb.x, 0.f);
    float v1 = fmaxf(acc1 * di + bb.y, 0.f);
    out[(size_t)node * 64 + lane] = pack2(v0, v1);
}

// ---------------- entity mean pool (bf16 in/out): wave per row ----------------
__global__ __launch_bounds__(256) void k_pool_b(const unsigned int* __restrict__ h,
                                                const int* __restrict__ ent,
                                                unsigned int* __restrict__ out) {
    int r = blockIdx.x * 4 + (threadIdx.x >> 6);
    int lane = threadIdx.x & 63;
    float a0 = 0.f, a1 = 0.f;
    int cnt = 0;
#pragma unroll
    for (int m = 0; m < 20; ++m) {
        int id = ent[r * 20 + m];
        if (id >= 0) {
            unsigned int q = h[(size_t)id * 64 + lane];
            a0 += blo(q); a1 += bhi(q); cnt++;
        }
    }
    float inv = 1.f / (float)max(cnt, 1);
    out[(size_t)r * 64 + lane] = pack2(a0 * inv, a1 * inv);
}

// ---------------- MLP fc1+fc2 fused (MFMA): logacc[row] += sum_col relu(...)*fc2w
__global__ __launch_bounds__(256) void k_mlp1_mfma(const bf16_t* __restrict__ bertb,
                                                   const bf16_t* __restrict__ gnnb,
                                                   const bf16_t* __restrict__ fwt,  // [448][896]
                                                   const float* __restrict__ fb,
                                                   const float* __restrict__ w2,   // fc2_w [448]
                                                   float* __restrict__ logacc) {
    __shared__ bf16_t As[64 * 136];
    __shared__ bf16_t Bs[64 * 136];
    int t = threadIdx.x;
    int wave = t >> 6, lane = t & 63, quad = lane >> 4, l16 = lane & 15;
    int r0 = blockIdx.x * 64, c0 = blockIdx.y * 64;
    facc4 acc[4];
#pragma unroll
    for (int nt = 0; nt < 4; ++nt) acc[nt] = (facc4){0.f, 0.f, 0.f, 0.f};

    for (int ks = 0; ks < 7; ++ks) {
#pragma unroll
        for (int i = 0; i < 4; ++i) {
            int chunk = t + i * 256;
            int row = chunk >> 4, c8 = (chunk & 15) << 3;
            int gr = r0 + row;
            const bf16_t* srcp = (ks < 6) ? &bertb[(size_t)gr * 768 + ks * 128 + c8]
                                          : &gnnb[(size_t)gr * 128 + c8];
            *(uint4*)&As[row * 136 + c8] = *(const uint4*)srcp;
        }
#pragma unroll
        for (int i = 0; i < 4; ++i) {
            int chunk = t + i * 256;
            int row = chunk >> 4, c8 = (chunk & 15) << 3;
            *(uint4*)&Bs[row * 136 + c8] =
                *(const uint4*)&fwt[(size_t)(c0 + row) * 896 + ks * 128 + c8];
        }
        __syncthreads();
        int arow = (wave << 4) + l16;
#pragma unroll
        for (int sub = 0; sub < 4; ++sub) {
            int kk = sub * 32 + quad * 8;
            bfrag8 af = *(const bfrag8*)&As[arow * 136 + kk];
#pragma unroll
            for (int nt = 0; nt < 4; ++nt) {
                bfrag8 bf = *(const bfrag8*)&Bs[(nt * 16 + l16) * 136 + kk];
                acc[nt] = __builtin_amdgcn_mfma_f32_16x16x32_bf16(af, bf, acc[nt], 0, 0, 0);
            }
        }
        __syncthreads();
    }
    // epilogue: bias+relu, dot with fc2w slice, reduce over the 16 col-lanes
    int rbase = r0 + (wave << 4) + quad * 4;
    float part[4] = {0.f, 0.f, 0.f, 0.f};
#pragma unroll
    for (int nt = 0; nt < 4; ++nt) {
        int col = c0 + nt * 16 + l16;
        float bb = fb[col];
        float ww = w2[col];
#pragma unroll
        for (int r = 0; r < 4; ++r)
            part[r] += fmaxf(acc[nt][r] + bb, 0.f) * ww;
    }
#pragma unroll
    for (int m = 8; m >= 1; m >>= 1) {
#pragma unroll
        for (int r = 0; r < 4; ++r) part[r] += __shfl_xor(part[r], m, 64);
    }
    if (l16 == 0) {
#pragma unroll
        for (int r = 0; r < 4; ++r) atomicAdd(&logacc[rbase + r], part[r]);
    }
}

// ---------------- sigmoid(logacc + b) ----------------
__global__ void k_sig(const float* __restrict__ logacc, const float* __restrict__ b,
                      float* __restrict__ out, int B) {
    int i = blockIdx.x * 256 + threadIdx.x;
    if (i < B) out[i] = 1.f / (1.f + expf(-(logacc[i] + b[0])));
}

extern "C" void kernel_launch(void* const* d_in, const int* in_sizes, int n_in,
                              void* d_out, int out_size, void* d_ws, size_t ws_size,
                              hipStream_t stream) {
    const float* bert = (const float*)d_in[0];
    const float* x    = (const float*)d_in[1];
    const int*   ei   = (const int*)d_in[2];
    const int*   ent  = (const int*)d_in[3];
    const float* W1   = (const float*)d_in[4];
    const float* b1   = (const float*)d_in[5];
    const float* W2   = (const float*)d_in[6];
    const float* b2   = (const float*)d_in[7];
    const float* fc1w = (const float*)d_in[8];
    const float* fc1b = (const float*)d_in[9];
    const float* fc2w = (const float*)d_in[10];
    const float* fc2b = (const float*)d_in[11];
    float* out = (float*)d_out;

    const int N = in_sizes[1] / 128;   // 50000 (< 65536 required for 16-bit packing)
    const int E = in_sizes[2] / 2;     // 800000
    const int B = in_sizes[0] / 768;   // 4096

    const int* srcv = ei;
    const int* dstv = ei + E;

    char* wsp = (char*)d_ws;
    size_t off = 0;
    auto alloc = [&](size_t bytes) -> void* {
        void* p = wsp + off;
        off += (bytes + 255) & ~(size_t)255;
        return p;
    };
    float* dinv   = (float*)alloc((size_t)N * 4);
    int*   offs   = (int*)alloc((size_t)(N + 1) * 4);
    int*   bcnt   = (int*)alloc(NBUCK * 4);
    float* logacc = (float*)alloc((size_t)B * 4);
    unsigned int*   ebuf  = (unsigned int*)alloc((size_t)NBUCK * BCAP * 4);   // 8 MB
    unsigned short* csr16 = (unsigned short*)alloc((size_t)E * 2);
    bf16_t* bertb = (bf16_t*)alloc((size_t)B * 768 * 2);
    bf16_t* w1t   = (bf16_t*)alloc(128 * 128 * 2);
    bf16_t* w2t   = (bf16_t*)alloc(128 * 128 * 2);
    bf16_t* fwt   = (bf16_t*)alloc((size_t)896 * 448 * 2);
    unsigned char* g8buf = (unsigned char*)alloc((size_t)N * 128);   // fp8 h' = (hW)*dinv
    bf16_t* hbuf  = (bf16_t*)alloc((size_t)N * 128 * 2);             // agg out (post-relu)
    bf16_t* gnnb  = (bf16_t*)alloc((size_t)B * 128 * 2);
    (void)ws_size; (void)n_in; (void)out_size;

    int nb8 = B * 768 / 8;
    int ncvt = (nb8 + 255) / 256;
    int nprep = ncvt + 128 + 98 + 1;
    k_prep<<<nprep, 256, 0, stream>>>(bert, (unsigned int*)bertb, nb8,
                                      W1, (unsigned short*)w1t, W2, (unsigned short*)w2t,
                                      fc1w, (unsigned short*)fwt, bcnt, logacc);
    k_bin2  <<<(E + 4095) / 4096, 256, 0, stream>>>(srcv, dstv, bcnt, ebuf, E, N);
    k_build2<<<NBUCK, 256, 0, stream>>>(ebuf, bcnt, offs, dinv, csr16, N, E);

    int gb = (N + 63) / 64;
    k_gemm_f32a<<<gb, 256, 0, stream>>>(x, w1t, dinv, g8buf, N);
    k_agg_b<<<(N + 3) / 4, 256, 0, stream>>>((const unsigned short*)g8buf, csr16, offs, dinv, b1,
                                             (unsigned int*)hbuf, N);
    k_gemm_nn128<<<gb, 256, 0, stream>>>(hbuf, w2t, dinv, g8buf, N);
    k_agg_b<<<(N + 3) / 4, 256, 0, stream>>>((const unsigned short*)g8buf, csr16, offs, dinv, b2,
                                             (unsigned int*)hbuf, N);
    k_pool_b<<<B / 4, 256, 0, stream>>>((const unsigned int*)hbuf, ent, (unsigned int*)gnnb);
    k_mlp1_mfma<<<dim3(B / 64, 7), 256, 0, stream>>>(bertb, gnnb, fwt, fc1b, fc2w, logacc);
    k_sig<<<(B + 255) / 256, 256, 0, stream>>>(logacc, fc2b, out, B);
}